// Round 5
// baseline (3612.564 us; speedup 1.0000x reference)
//
#include <hip/hip_runtime.h>

// ---------------------------------------------------------------------------
// GraphCast-style GNN on MI355X (gfx950). Round 5:
//  - GEMM1 A-operand loaded per-lane directly global->register fragments:
//    NO LDS staging, NO per-K-step barriers (waves fully decoupled).
//    A ping-pong prefetch (dist-1 step), B frags JIT single-buffer reload.
//  - edges sorted by dst once: aggregation gather is contiguous (perm-free),
//    dst-row gather in edge MLP is sequential/L1-hot.
//  - LDS only holds h (half-split) + LN scratch; 3 barriers per block total.
// ---------------------------------------------------------------------------

typedef __attribute__((ext_vector_type(8))) short bf16x8;
typedef __attribute__((ext_vector_type(4))) float f32x4;
typedef unsigned short u16;

#define NNODES 32768
#define NEDGES 196608

#define MFMA16(a, b, c) __builtin_amdgcn_mfma_f32_16x16x32_bf16((a), (b), (c), 0, 0, 0)

__device__ __forceinline__ u16 f2bf(float f) {
    unsigned u = __float_as_uint(f);
    unsigned r = (u + 0x7FFFu + ((u >> 16) & 1u)) >> 16;  // RNE
    return (u16)r;
}
__device__ __forceinline__ float bf2f(u16 b) {
    return __uint_as_float(((unsigned)b) << 16);
}
__device__ __forceinline__ unsigned pack2(float a, float b) {
    return (unsigned)f2bf(a) | ((unsigned)f2bf(b) << 16);
}

// ---------------------------------------------------------------------------
// Input transpose (x only): W (K, Nout) fp32 -> WT (NP, Kpad) bf16
// ---------------------------------------------------------------------------
__global__ void wtrans_kernel(const float* __restrict__ W, u16* __restrict__ WT,
                              int K, int Nout, int Kpad, int NP) {
    __shared__ u16 tile[32][33];
    const int k0 = blockIdx.x * 32, n0 = blockIdx.y * 32;
    const int tx = threadIdx.x & 31, ty = threadIdx.x >> 5;  // 32 x 8
    #pragma unroll
    for (int i = 0; i < 4; i++) {
        int k = k0 + ty + 8 * i, n = n0 + tx;
        float v = (k < K && n < Nout) ? W[(size_t)k * Nout + n] : 0.f;
        tile[ty + 8 * i][tx] = f2bf(v);
    }
    __syncthreads();
    #pragma unroll
    for (int i = 0; i < 4; i++) {
        int n = n0 + ty + 8 * i, k = k0 + tx;
        if (n < NP && k < Kpad) WT[(size_t)n * Kpad + k] = tile[tx][ty + 8 * i];
    }
}

// ---------------------------------------------------------------------------
// Fragment-major weight pack: W (batch, K, N) fp32 -> frags bf16.
// Frag (ks, cb): lane l, elem j  <-  W[k = ks*32 + (l>>4)*8 + j][n = cb*16 + (l&15)]
// ---------------------------------------------------------------------------
__global__ void fragpack_kernel(const float* __restrict__ W, u16* __restrict__ F,
                                int K, int N, int CB, int NFRAG) {
    int b = blockIdx.z;
    int fr = blockIdx.x * 4 + (threadIdx.x >> 6);
    if (fr >= NFRAG) return;
    int l = threadIdx.x & 63;
    int ks = fr / CB, cb = fr % CB;
    int k0 = ks * 32 + ((l >> 4) * 8);
    int n = cb * 16 + (l & 15);
    u16 v[8];
    #pragma unroll
    for (int j = 0; j < 8; j++) {
        int k = k0 + j;
        float x = (k < K && n < N) ? W[((size_t)b * K + k) * N + n] : 0.f;
        v[j] = f2bf(x);
    }
    *(uint4*)(F + (((size_t)b * NFRAG + fr) * 64 + l) * 8) = *(const uint4*)v;
}

// ---------------------------------------------------------------------------
// edge_index normalization (int64 payload -> int32 [src | dst])
// ---------------------------------------------------------------------------
__global__ void idx_norm_kernel(const int* __restrict__ raw, int* __restrict__ sd) {
    __shared__ int nz;
    if (threadIdx.x == 0) nz = 0;
    __syncthreads();
    for (int i = threadIdx.x; i < 512; i += 256)
        if (raw[2 * i + 1] != 0) atomicAdd(&nz, 1);
    __syncthreads();
    const bool is64 = (nz == 0);
    int idx = blockIdx.x * 256 + threadIdx.x;
    if (idx < 2 * NEDGES) sd[idx] = is64 ? raw[2 * idx] : raw[idx];
}

// ---------------------------------------------------------------------------
// CSR build (by dst) + edge sort.
// ---------------------------------------------------------------------------
__global__ void csr_count_kernel(const int* __restrict__ dsti, int* __restrict__ deg) {
    int e = blockIdx.x * 256 + threadIdx.x;
    atomicAdd(&deg[dsti[e]], 1);
}

__global__ void csr_scan_kernel(const int* __restrict__ deg, int* __restrict__ off,
                                int* __restrict__ cur) {
    __shared__ int part[1024];
    const int t = threadIdx.x;
    int local[32];
    int s = 0;
    #pragma unroll
    for (int i = 0; i < 32; i++) { local[i] = deg[t * 32 + i]; s += local[i]; }
    part[t] = s;
    __syncthreads();
    for (int d = 1; d < 1024; d <<= 1) {
        int v = (t >= d) ? part[t - d] : 0;
        __syncthreads();
        part[t] += v;
        __syncthreads();
    }
    int excl = (t == 0) ? 0 : part[t - 1];
    #pragma unroll
    for (int i = 0; i < 32; i++) {
        off[t * 32 + i] = excl;
        cur[t * 32 + i] = excl;
        excl += local[i];
    }
    if (t == 1023) off[NNODES] = excl;
}

__global__ void csr_fill_kernel(const int* __restrict__ dsti, int* __restrict__ cur,
                                int* __restrict__ perm) {
    int e = blockIdx.x * 256 + threadIdx.x;
    int pos = atomicAdd(&cur[dsti[e]], 1);
    perm[pos] = e;
}

// sorted-order src/dst arrays
__global__ void esort_kernel(const int* __restrict__ sd, const int* __restrict__ perm,
                             int* __restrict__ srcS, int* __restrict__ dstS) {
    int i = blockIdx.x * 256 + threadIdx.x;
    int e = perm[i];
    srcS[i] = sd[e];
    dstS[i] = sd[NEDGES + e];
}

// aggB[n][c] = sum over sorted edge rows off[n]..off[n+1] of edge_b[i][c]
__global__ void gather_kernel(const u16* __restrict__ edge_b,
                              const int* __restrict__ off, u16* __restrict__ aggB) {
    int idx = blockIdx.x * 256 + threadIdx.x;  // N*32 threads
    int n = idx >> 5, c = (idx & 31) * 4;
    int a = off[n], b = off[n + 1];
    float s0 = 0.f, s1 = 0.f, s2 = 0.f, s3 = 0.f;
    for (int i = a; i < b; i++) {
        uint2 v = *(const uint2*)(edge_b + (size_t)i * 128 + c);
        s0 += bf2f((u16)(v.x & 0xffff)); s1 += bf2f((u16)(v.x >> 16));
        s2 += bf2f((u16)(v.y & 0xffff)); s3 += bf2f((u16)(v.y >> 16));
    }
    uint2 o;
    o.x = pack2(s0, s1);
    o.y = pack2(s2, s3);
    *(uint2*)(aggB + (size_t)n * 128 + c) = o;
}

// ---------------------------------------------------------------------------
// Fused 2-layer MLP.  Block = 256 threads (4 waves) = 64 rows.
// GEMM1: barrier-free. Each lane loads its own A fragments (row = m*16+llo,
//        16B at k-offset lhi*8) directly global->reg; A ping-pong prefetch,
//        B frags JIT-reloaded after last use. Wave owns cols cb = j*4+wave.
// GEMM2: h via LDS (half-split), W2 global->reg ping-pong; cross-wave LN.
// IN: 0=edge(src|dst|edge)  1=node(node|agg)  2=direct bf16 stride A1S
//     3=raw edge feats via perm (p.src = perm)
// ---------------------------------------------------------------------------
struct MlpP {
    const u16* A1;
    const u16* A1b;
    const float* Araw;
    const int* src;
    const int* dsti;
    const u16* W1F;   // frag-major [K1/32][NH/16][64][8]
    const u16* W2F;   // frag-major [NH/32][NFRAG2][64][8]
    const float* b1;
    const float* b2;
    const float* g;
    const float* bt;
    const float* resid;
    float* outF;
    u16* outB;
    float* outDec;
};

template <int K1, int NH, int NOUT, int IN, int OUT, int A1S>
__global__ __launch_bounds__(256, 2) void mlp_kernel(MlpP p) {
    static_assert(K1 % 32 == 0 && NH % 128 == 0, "dims");
    constexpr int KSTEPS = K1 / 32;
    constexpr int NT1 = NH / 64;                 // GEMM1 col-frags per wave
    constexpr int CB1 = NH / 16;
    constexpr int NFRAG2 = (NOUT + 15) / 16;
    constexpr int NT2 = (NFRAG2 + 3) / 4;        // GEMM2 frags per wave
    constexpr int S2 = NH / 64;                  // GEMM2 32-k steps per half
    constexpr int SH2 = NH / 2 + 8;              // padded h stride (u16)
    constexpr int SMEM_I = 64 * SH2 * 2;
    constexpr int SMEM = SMEM_I + 2560;          // + LN scratch

    __shared__ __align__(16) char smem[SMEM];
    u16* sH = (u16*)smem;                        // [64][SH2]
    float* sS1 = (float*)(smem + SMEM_I);        // [4][64]
    float* sS2 = sS1 + 256;                      // [4][64]
    float* sMu = sS1 + 512;                      // [64]
    float* sRs = sS1 + 576;                      // [64]

    const int tid = threadIdx.x;
    const int wave = tid >> 6, lane = tid & 63;
    const int lhi = lane >> 4, llo = lane & 15;
    const int r0 = blockIdx.x * 64;
    const int ko = lhi * 8;                      // k-offset within a 32-k step

    // Per-lane row indices for the 4 A row-fragments (row = m*16 + llo).
    int rs[4], rd[4];
    if constexpr (IN == 0) {
        #pragma unroll
        for (int m = 0; m < 4; m++) {
            rs[m] = p.src[r0 + m * 16 + llo];
            rd[m] = p.dsti[r0 + m * 16 + llo];
        }
    } else if constexpr (IN == 3) {
        #pragma unroll
        for (int m = 0; m < 4; m++) rs[m] = p.src[r0 + m * 16 + llo];  // perm
    }

    auto loadA4 = [&](int ks, bf16x8 (&d)[4]) {
        const int kb = ks * 32;  // step-uniform; segment branches fold at unroll
        if constexpr (IN == 0) {
            if (kb < 256) {
                #pragma unroll
                for (int m = 0; m < 4; m++)
                    d[m] = *(const bf16x8*)(p.A1 + (size_t)rs[m] * 256 + kb + ko);
            } else if (kb < 512) {
                #pragma unroll
                for (int m = 0; m < 4; m++)
                    d[m] = *(const bf16x8*)(p.A1 + (size_t)rd[m] * 256 + (kb - 256) + ko);
            } else {
                #pragma unroll
                for (int m = 0; m < 4; m++)
                    d[m] = *(const bf16x8*)(p.A1b + (size_t)(r0 + m * 16 + llo) * 128 + (kb - 512) + ko);
            }
        } else if constexpr (IN == 1) {
            if (kb < 256) {
                #pragma unroll
                for (int m = 0; m < 4; m++)
                    d[m] = *(const bf16x8*)(p.A1 + (size_t)(r0 + m * 16 + llo) * 256 + kb + ko);
            } else {
                #pragma unroll
                for (int m = 0; m < 4; m++)
                    d[m] = *(const bf16x8*)(p.A1b + (size_t)(r0 + m * 16 + llo) * 128 + (kb - 256) + ko);
            }
        } else if constexpr (IN == 2) {
            #pragma unroll
            for (int m = 0; m < 4; m++)
                d[m] = *(const bf16x8*)(p.A1 + (size_t)(r0 + m * 16 + llo) * A1S + kb + ko);
        } else {  // IN == 3: raw edge feats (3 -> 32 padded), single step
            #pragma unroll
            for (int m = 0; m < 4; m++) {
                u16 v[8] = {0, 0, 0, 0, 0, 0, 0, 0};
                if (lhi == 0) {
                    const float* q = p.Araw + (size_t)rs[m] * 3;
                    v[0] = f2bf(q[0]); v[1] = f2bf(q[1]); v[2] = f2bf(q[2]);
                }
                d[m] = *(const bf16x8*)v;
            }
        }
    };
    auto loadB1frag = [&](int ks, int j) -> bf16x8 {
        int cb = j * 4 + wave;
        return *(const bf16x8*)(p.W1F + ((size_t)(ks * CB1 + cb) * 64 + lane) * 8);
    };

    const f32x4 fz = {0.f, 0.f, 0.f, 0.f};
    f32x4 acc[4][NT1];
    #pragma unroll
    for (int m = 0; m < 4; m++)
        #pragma unroll
        for (int j = 0; j < NT1; j++) acc[m][j] = fz;

    bf16x8 paA[4], paB[4];
    bf16x8 pb[NT1];
    loadA4(0, paA);
    #pragma unroll
    for (int j = 0; j < NT1; j++) pb[j] = loadB1frag(0, j);

    // ---------------- GEMM1: barrier-free, per-lane A frags ---------------
    #pragma unroll
    for (int ks = 0; ks < KSTEPS; ks++) {
        bf16x8 (&cur)[4] = (ks & 1) ? paB : paA;
        bf16x8 (&nxt)[4] = (ks & 1) ? paA : paB;
        if (ks + 1 < KSTEPS) loadA4(ks + 1, nxt);   // dist-1 prefetch
        #pragma unroll
        for (int j = 0; j < NT1; j++) {
            #pragma unroll
            for (int m = 0; m < 4; m++) acc[m][j] = MFMA16(cur[m], pb[j], acc[m][j]);
            if (ks + 1 < KSTEPS) pb[j] = loadB1frag(ks + 1, j);  // JIT reload
        }
    }

    // ---------------- phase 2: h halves -> LDS, GEMM2 ping-pong W2 --------
    f32x4 acc2[4][NT2];
    #pragma unroll
    for (int m = 0; m < 4; m++)
        #pragma unroll
        for (int j = 0; j < NT2; j++) acc2[m][j] = fz;

    auto loadW2 = [&](int g, bf16x8 (&d)[NT2]) {
        #pragma unroll
        for (int j = 0; j < NT2; j++) {
            int f = j * 4 + wave;
            if (NFRAG2 % 4 == 0 || f < NFRAG2)
                d[j] = *(const bf16x8*)(p.W2F + ((size_t)(g * NFRAG2 + f) * 64 + lane) * 8);
        }
    };
    bf16x8 pw0[NT2], pw1[NT2];
    loadW2(0, pw0);
    loadW2(1, pw1);

    #pragma unroll
    for (int half = 0; half < 2; half++) {
        // h-write: this wave's col-blocks of this half (SiLU via fast rcp)
        #pragma unroll
        for (int j = half * (NT1 / 2); j < (half + 1) * (NT1 / 2); j++) {
            int c = (j * 4 + wave) * 16 + llo;
            int coll = c - half * (NH / 2);
            float bias = p.b1[c];
            #pragma unroll
            for (int m = 0; m < 4; m++)
                #pragma unroll
                for (int r = 0; r < 4; r++) {
                    int row = m * 16 + lhi * 4 + r;
                    float v = acc[m][j][r] + bias;
                    float sgm = __builtin_amdgcn_rcpf(1.f + __expf(-v));
                    sH[row * SH2 + coll] = f2bf(v * sgm);
                }
        }
        __syncthreads();
        #pragma unroll
        for (int s = 0; s < S2; s++) {
            const int g = half * S2 + s;
            bf16x8 (&pwc)[NT2] = (g & 1) ? pw1 : pw0;
            bf16x8 a2[4];
            #pragma unroll
            for (int m = 0; m < 4; m++)
                a2[m] = *(const bf16x8*)(sH + (m * 16 + llo) * SH2 + s * 32 + lhi * 8);
            #pragma unroll
            for (int j = 0; j < NT2; j++)
                if (NFRAG2 % 4 == 0 || j * 4 + wave < NFRAG2)
                    #pragma unroll
                    for (int m = 0; m < 4; m++)
                        acc2[m][j] = MFMA16(a2[m], pwc[j], acc2[m][j]);
            if (g + 2 < 2 * S2) loadW2(g + 2, pwc);
        }
        __syncthreads();
    }

    // ---------------- epilogue ----------------
    if constexpr (OUT == 0) {  // +bias +resid, LayerNorm (NFRAG2 % 4 == 0 here)
        float ps1[4][4], ps2[4][4];
        #pragma unroll
        for (int m = 0; m < 4; m++)
            #pragma unroll
            for (int r = 0; r < 4; r++) { ps1[m][r] = 0.f; ps2[m][r] = 0.f; }
        #pragma unroll
        for (int j = 0; j < NT2; j++) {
            int col = (j * 4 + wave) * 16 + llo;
            float bias = p.b2[col];
            #pragma unroll
            for (int m = 0; m < 4; m++)
                #pragma unroll
                for (int r = 0; r < 4; r++) {
                    int row = m * 16 + lhi * 4 + r;
                    float v = acc2[m][j][r] + bias + p.resid[(size_t)(r0 + row) * NOUT + col];
                    acc2[m][j][r] = v;
                    ps1[m][r] += v;
                    ps2[m][r] += v * v;
                }
        }
        #pragma unroll
        for (int mm = 1; mm < 16; mm <<= 1)
            #pragma unroll
            for (int m = 0; m < 4; m++)
                #pragma unroll
                for (int r = 0; r < 4; r++) {
                    ps1[m][r] += __shfl_xor(ps1[m][r], mm, 64);
                    ps2[m][r] += __shfl_xor(ps2[m][r], mm, 64);
                }
        if (llo == 0) {
            #pragma unroll
            for (int m = 0; m < 4; m++)
                #pragma unroll
                for (int r = 0; r < 4; r++) {
                    int row = m * 16 + lhi * 4 + r;
                    sS1[wave * 64 + row] = ps1[m][r];
                    sS2[wave * 64 + row] = ps2[m][r];
                }
        }
        __syncthreads();
        if (tid < 64) {
            float a = sS1[tid] + sS1[64 + tid] + sS1[128 + tid] + sS1[192 + tid];
            float b = sS2[tid] + sS2[64 + tid] + sS2[128 + tid] + sS2[192 + tid];
            float mu = a * (1.f / NOUT);
            float var = b * (1.f / NOUT) - mu * mu;
            sMu[tid] = mu;
            sRs[tid] = rsqrtf(var + 1e-5f);
        }
        __syncthreads();
        #pragma unroll
        for (int j = 0; j < NT2; j++) {
            int col = (j * 4 + wave) * 16 + llo;
            float gg = p.g[col], bb = p.bt[col];
            #pragma unroll
            for (int m = 0; m < 4; m++)
                #pragma unroll
                for (int r = 0; r < 4; r++) {
                    int row = m * 16 + lhi * 4 + r;
                    float v = (acc2[m][j][r] - sMu[row]) * sRs[row] * gg + bb;
                    size_t o = (size_t)(r0 + row) * NOUT + col;
                    p.outF[o] = v;
                    p.outB[o] = f2bf(v);
                }
        }
    } else if constexpr (OUT == 1) {  // plain +bias
        #pragma unroll
        for (int j = 0; j < NT2; j++) {
            int col = (j * 4 + wave) * 16 + llo;
            float bias = p.b2[col];
            #pragma unroll
            for (int m = 0; m < 4; m++)
                #pragma unroll
                for (int r = 0; r < 4; r++) {
                    int row = m * 16 + lhi * 4 + r;
                    float v = acc2[m][j][r] + bias;
                    size_t o = (size_t)(r0 + row) * NOUT + col;
                    p.outF[o] = v;
                    p.outB[o] = f2bf(v);
                }
        }
    } else {  // decoder: transposed fp32 store, ragged frags, cols < 69
        #pragma unroll
        for (int j = 0; j < NT2; j++) {
            int f = j * 4 + wave;
            int col = f * 16 + llo;
            if (f < NFRAG2 && col < 69) {
                float bias = p.b2[col];
                #pragma unroll
                for (int m = 0; m < 4; m++)
                    #pragma unroll
                    for (int r = 0; r < 4; r++) {
                        int row = m * 16 + lhi * 4 + r;
                        p.outDec[(size_t)col * NNODES + (r0 + row)] = acc2[m][j][r] + bias;
                    }
            }
        }
    }
}

// ---------------------------------------------------------------------------
extern "C" void kernel_launch(void* const* d_in, const int* in_sizes, int n_in,
                              void* d_out, int out_size, void* d_ws, size_t ws_size,
                              hipStream_t stream) {
    (void)in_sizes; (void)n_in; (void)out_size; (void)ws_size;

    const float* x       = (const float*)d_in[0];
    const int*   eidx    = (const int*)d_in[1];
    const float* raw_e   = (const float*)d_in[2];
    const float* enc_w1  = (const float*)d_in[3];
    const float* enc_b1  = (const float*)d_in[4];
    const float* enc_w2  = (const float*)d_in[5];
    const float* enc_b2  = (const float*)d_in[6];
    const float* eenc_w1 = (const float*)d_in[7];
    const float* eenc_b1 = (const float*)d_in[8];
    const float* eenc_w2 = (const float*)d_in[9];
    const float* eenc_b2 = (const float*)d_in[10];
    const float* pe_w1   = (const float*)d_in[11];
    const float* pe_b1   = (const float*)d_in[12];
    const float* pe_w2   = (const float*)d_in[13];
    const float* pe_b2   = (const float*)d_in[14];
    const float* pe_g    = (const float*)d_in[15];
    const float* pe_bt   = (const float*)d_in[16];
    const float* pn_w1   = (const float*)d_in[17];
    const float* pn_b1   = (const float*)d_in[18];
    const float* pn_w2   = (const float*)d_in[19];
    const float* pn_b2   = (const float*)d_in[20];
    const float* pn_g    = (const float*)d_in[21];
    const float* pn_bt   = (const float*)d_in[22];
    const float* dec_w1  = (const float*)d_in[23];
    const float* dec_b1  = (const float*)d_in[24];
    const float* dec_w2  = (const float*)d_in[25];
    const float* dec_b2  = (const float*)d_in[26];

    // ---- workspace carve ----
    char* ws = (char*)d_ws;
    size_t o = 0;
    auto alloc = [&](size_t bytes) -> void* {
        void* p = ws + o;
        o += (bytes + 255) & ~(size_t)255;
        return p;
    };
    float* node_f = (float*)alloc((size_t)NNODES * 256 * 4);
    u16*   node_b = (u16*)  alloc((size_t)NNODES * 256 * 2);
    float* edge_f = (float*)alloc((size_t)NEDGES * 128 * 4);   // sorted order
    u16*   edge_b = (u16*)  alloc((size_t)NEDGES * 128 * 2);   // sorted order
    u16*   aggB   = (u16*)  alloc((size_t)NNODES * 128 * 2);
    u16*   xT     = (u16*)  alloc((size_t)NNODES * 96 * 2);
    u16*   encw1F  = (u16*)alloc((size_t)96 * 256 * 2);
    u16*   encw2F  = (u16*)alloc((size_t)256 * 256 * 2);
    u16*   eencw1F = (u16*)alloc((size_t)32 * 128 * 2);
    u16*   eencw2F = (u16*)alloc((size_t)128 * 128 * 2);
    u16*   pew1F   = (u16*)alloc((size_t)8 * 640 * 512 * 2);
    u16*   pew2F   = (u16*)alloc((size_t)8 * 512 * 128 * 2);
    u16*   pnw1F   = (u16*)alloc((size_t)8 * 384 * 512 * 2);
    u16*   pnw2F   = (u16*)alloc((size_t)8 * 512 * 256 * 2);
    u16*   decw1F  = (u16*)alloc((size_t)256 * 256 * 2);
    u16*   decw2F  = (u16*)alloc((size_t)256 * 80 * 2);
    int*   sd     = (int*)  alloc((size_t)2 * NEDGES * 4);
    int*   deg    = (int*)  alloc((size_t)NNODES * 4);
    int*   off_   = (int*)  alloc((size_t)(NNODES + 1) * 4);
    int*   cur    = (int*)  alloc((size_t)NNODES * 4);
    int*   perm   = (int*)  alloc((size_t)NEDGES * 4);
    int*   srcS   = (int*)  alloc((size_t)NEDGES * 4);
    int*   dstS   = (int*)  alloc((size_t)NEDGES * 4);

    // ---- weight prep: fragment-major pack ----
    auto FP = [&](const float* W, u16* F, int K, int N, int KB, int CB, int batch) {
        int nf = KB * CB;
        dim3 g((nf + 3) / 4, 1, batch);
        fragpack_kernel<<<g, 256, 0, stream>>>(W, F, K, N, CB, nf);
    };
    FP(enc_w1,  encw1F,  70,  256, 3,  16, 1);
    FP(enc_w2,  encw2F,  256, 256, 8,  16, 1);
    FP(eenc_w1, eencw1F, 3,   128, 1,  8,  1);
    FP(eenc_w2, eencw2F, 128, 128, 4,  8,  1);
    FP(pe_w1,   pew1F,   640, 512, 20, 32, 8);
    FP(pe_w2,   pew2F,   512, 128, 16, 8,  8);
    FP(pn_w1,   pnw1F,   384, 512, 12, 32, 8);
    FP(pn_w2,   pnw2F,   512, 256, 16, 16, 8);
    FP(dec_w1,  decw1F,  256, 256, 8,  16, 1);
    FP(dec_w2,  decw2F,  256, 69,  8,  5,  1);
    {   // x (70, N) -> xT (N, 96) bf16
        dim3 g(96 / 32, NNODES / 32, 1);
        wtrans_kernel<<<g, 256, 0, stream>>>(x, xT, 70, NNODES, 96, NNODES);
    }

    // ---- indices + CSR + edge sort ----
    idx_norm_kernel<<<1536, 256, 0, stream>>>(eidx, sd);
    hipMemsetAsync(deg, 0, (size_t)NNODES * 4, stream);
    csr_count_kernel<<<NEDGES / 256, 256, 0, stream>>>(sd + NEDGES, deg);
    csr_scan_kernel<<<1, 1024, 0, stream>>>(deg, off_, cur);
    csr_fill_kernel<<<NEDGES / 256, 256, 0, stream>>>(sd + NEDGES, cur, perm);
    esort_kernel<<<NEDGES / 256, 256, 0, stream>>>(sd, perm, srcS, dstS);

    // ---- encoders ----
    {
        MlpP p{};
        p.A1 = xT; p.W1F = encw1F; p.W2F = encw2F; p.b1 = enc_b1; p.b2 = enc_b2;
        p.outF = node_f; p.outB = node_b;
        mlp_kernel<96, 256, 256, 2, 1, 96><<<NNODES / 64, 256, 0, stream>>>(p);
    }
    {   // edge encoder: reads raw feats via perm, writes sorted order
        MlpP p{};
        p.Araw = raw_e; p.src = perm;
        p.W1F = eencw1F; p.W2F = eencw2F; p.b1 = eenc_b1; p.b2 = eenc_b2;
        p.outF = edge_f; p.outB = edge_b;
        mlp_kernel<32, 128, 128, 3, 1, 0><<<NEDGES / 64, 256, 0, stream>>>(p);
    }

    // ---- processor layers ----
    for (int l = 0; l < 8; l++) {
        {
            MlpP p{};
            p.A1 = node_b; p.A1b = edge_b; p.src = srcS; p.dsti = dstS;
            p.W1F = pew1F + (size_t)l * 640 * 512;
            p.W2F = pew2F + (size_t)l * 512 * 128;
            p.b1 = pe_b1 + l * 512; p.b2 = pe_b2 + l * 128;
            p.g = pe_g + l * 128; p.bt = pe_bt + l * 128;
            p.resid = edge_f; p.outF = edge_f; p.outB = edge_b;
            mlp_kernel<640, 512, 128, 0, 0, 0><<<NEDGES / 64, 256, 0, stream>>>(p);
        }
        gather_kernel<<<NNODES * 32 / 256, 256, 0, stream>>>(edge_b, off_, aggB);
        {
            MlpP p{};
            p.A1 = node_b; p.A1b = aggB;
            p.W1F = pnw1F + (size_t)l * 384 * 512;
            p.W2F = pnw2F + (size_t)l * 512 * 256;
            p.b1 = pn_b1 + l * 512; p.b2 = pn_b2 + l * 256;
            p.g = pn_g + l * 256; p.bt = pn_bt + l * 256;
            p.resid = node_f; p.outF = node_f; p.outB = node_b;
            mlp_kernel<384, 512, 256, 1, 0, 0><<<NNODES / 64, 256, 0, stream>>>(p);
        }
    }

    // ---- decoder ----
    {
        MlpP p{};
        p.A1 = node_b; p.W1F = decw1F; p.W2F = decw2F; p.b1 = dec_b1; p.b2 = dec_b2;
        p.outDec = (float*)d_out;
        mlp_kernel<256, 256, 80, 2, 2, 256><<<NNODES / 64, 256, 0, stream>>>(p);
    }
}

// Round 6
// 3295.187 us; speedup vs baseline: 1.0963x; 1.0963x over previous
//
#include <hip/hip_runtime.h>

// ---------------------------------------------------------------------------
// GraphCast-style GNN on MI355X (gfx950). Round 6:
//  - full A-panel (K<=512) staged to LDS ONCE (64KB/WG, 2 blocks/CU):
//    GEMM1 is barrier-free; XOR-swizzled chunks -> conflict-balanced reads.
//    Edge kernel's K=512..639 tail (contiguous edge rows) per-lane direct.
//  - residual stream carried in bf16, updated in-place (edge_b / node_b):
//    drops the fp32 edge_f/node_f streams (~2.1 GB HBM saved).
//  - B operands (W1/W2 frag-major) global->reg ping-pong as in round 4.
// ---------------------------------------------------------------------------

typedef __attribute__((ext_vector_type(8))) short bf16x8;
typedef __attribute__((ext_vector_type(4))) float f32x4;
typedef unsigned short u16;

#define NNODES 32768
#define NEDGES 196608

#define MFMA16(a, b, c) __builtin_amdgcn_mfma_f32_16x16x32_bf16((a), (b), (c), 0, 0, 0)

__device__ __forceinline__ u16 f2bf(float f) {
    unsigned u = __float_as_uint(f);
    unsigned r = (u + 0x7FFFu + ((u >> 16) & 1u)) >> 16;  // RNE
    return (u16)r;
}
__device__ __forceinline__ float bf2f(u16 b) {
    return __uint_as_float(((unsigned)b) << 16);
}
__device__ __forceinline__ unsigned pack2(float a, float b) {
    return (unsigned)f2bf(a) | ((unsigned)f2bf(b) << 16);
}

// ---------------------------------------------------------------------------
// Input transpose (x only): W (K, Nout) fp32 -> WT (NP, Kpad) bf16
// ---------------------------------------------------------------------------
__global__ void wtrans_kernel(const float* __restrict__ W, u16* __restrict__ WT,
                              int K, int Nout, int Kpad, int NP) {
    __shared__ u16 tile[32][33];
    const int k0 = blockIdx.x * 32, n0 = blockIdx.y * 32;
    const int tx = threadIdx.x & 31, ty = threadIdx.x >> 5;  // 32 x 8
    #pragma unroll
    for (int i = 0; i < 4; i++) {
        int k = k0 + ty + 8 * i, n = n0 + tx;
        float v = (k < K && n < Nout) ? W[(size_t)k * Nout + n] : 0.f;
        tile[ty + 8 * i][tx] = f2bf(v);
    }
    __syncthreads();
    #pragma unroll
    for (int i = 0; i < 4; i++) {
        int n = n0 + ty + 8 * i, k = k0 + tx;
        if (n < NP && k < Kpad) WT[(size_t)n * Kpad + k] = tile[tx][ty + 8 * i];
    }
}

// ---------------------------------------------------------------------------
// Fragment-major weight pack: W (batch, K, N) fp32 -> frags bf16.
// Frag (ks, cb): lane l, elem j  <-  W[k = ks*32 + (l>>4)*8 + j][n = cb*16 + (l&15)]
// ---------------------------------------------------------------------------
__global__ void fragpack_kernel(const float* __restrict__ W, u16* __restrict__ F,
                                int K, int N, int CB, int NFRAG) {
    int b = blockIdx.z;
    int fr = blockIdx.x * 4 + (threadIdx.x >> 6);
    if (fr >= NFRAG) return;
    int l = threadIdx.x & 63;
    int ks = fr / CB, cb = fr % CB;
    int k0 = ks * 32 + ((l >> 4) * 8);
    int n = cb * 16 + (l & 15);
    u16 v[8];
    #pragma unroll
    for (int j = 0; j < 8; j++) {
        int k = k0 + j;
        float x = (k < K && n < N) ? W[((size_t)b * K + k) * N + n] : 0.f;
        v[j] = f2bf(x);
    }
    *(uint4*)(F + (((size_t)b * NFRAG + fr) * 64 + l) * 8) = *(const uint4*)v;
}

// ---------------------------------------------------------------------------
// edge_index normalization (int64 payload -> int32 [src | dst])
// ---------------------------------------------------------------------------
__global__ void idx_norm_kernel(const int* __restrict__ raw, int* __restrict__ sd) {
    __shared__ int nz;
    if (threadIdx.x == 0) nz = 0;
    __syncthreads();
    for (int i = threadIdx.x; i < 512; i += 256)
        if (raw[2 * i + 1] != 0) atomicAdd(&nz, 1);
    __syncthreads();
    const bool is64 = (nz == 0);
    int idx = blockIdx.x * 256 + threadIdx.x;
    if (idx < 2 * NEDGES) sd[idx] = is64 ? raw[2 * idx] : raw[idx];
}

// ---------------------------------------------------------------------------
// CSR build (by dst) + edge sort.
// ---------------------------------------------------------------------------
__global__ void csr_count_kernel(const int* __restrict__ dsti, int* __restrict__ deg) {
    int e = blockIdx.x * 256 + threadIdx.x;
    atomicAdd(&deg[dsti[e]], 1);
}

__global__ void csr_scan_kernel(const int* __restrict__ deg, int* __restrict__ off,
                                int* __restrict__ cur) {
    __shared__ int part[1024];
    const int t = threadIdx.x;
    int local[32];
    int s = 0;
    #pragma unroll
    for (int i = 0; i < 32; i++) { local[i] = deg[t * 32 + i]; s += local[i]; }
    part[t] = s;
    __syncthreads();
    for (int d = 1; d < 1024; d <<= 1) {
        int v = (t >= d) ? part[t - d] : 0;
        __syncthreads();
        part[t] += v;
        __syncthreads();
    }
    int excl = (t == 0) ? 0 : part[t - 1];
    #pragma unroll
    for (int i = 0; i < 32; i++) {
        off[t * 32 + i] = excl;
        cur[t * 32 + i] = excl;
        excl += local[i];
    }
    if (t == 1023) off[NNODES] = excl;
}

__global__ void csr_fill_kernel(const int* __restrict__ dsti, int* __restrict__ cur,
                                int* __restrict__ perm) {
    int e = blockIdx.x * 256 + threadIdx.x;
    int pos = atomicAdd(&cur[dsti[e]], 1);
    perm[pos] = e;
}

// sorted-order src/dst arrays
__global__ void esort_kernel(const int* __restrict__ sd, const int* __restrict__ perm,
                             int* __restrict__ srcS, int* __restrict__ dstS) {
    int i = blockIdx.x * 256 + threadIdx.x;
    int e = perm[i];
    srcS[i] = sd[e];
    dstS[i] = sd[NEDGES + e];
}

// aggB[n][c] = sum over sorted edge rows off[n]..off[n+1] of edge_b[i][c]
__global__ void gather_kernel(const u16* __restrict__ edge_b,
                              const int* __restrict__ off, u16* __restrict__ aggB) {
    int idx = blockIdx.x * 256 + threadIdx.x;  // N*32 threads
    int n = idx >> 5, c = (idx & 31) * 4;
    int a = off[n], b = off[n + 1];
    float s0 = 0.f, s1 = 0.f, s2 = 0.f, s3 = 0.f;
    for (int i = a; i < b; i++) {
        uint2 v = *(const uint2*)(edge_b + (size_t)i * 128 + c);
        s0 += bf2f((u16)(v.x & 0xffff)); s1 += bf2f((u16)(v.x >> 16));
        s2 += bf2f((u16)(v.y & 0xffff)); s3 += bf2f((u16)(v.y >> 16));
    }
    uint2 o;
    o.x = pack2(s0, s1);
    o.y = pack2(s2, s3);
    *(uint2*)(aggB + (size_t)n * 128 + c) = o;
}

// ---------------------------------------------------------------------------
// Fused 2-layer MLP.  Block = 256 threads (4 waves) = 64 rows.
// Phase 0: stage full A panel (K<=512) into LDS once (XOR-swizzled chunks).
// GEMM1:   barrier-free; A frags via ds_read ping-pong, B frags global->reg
//          dist-2 ping-pong. Edge tail steps (K>=512) per-lane direct loads
//          from contiguous edge rows. Wave owns col-blocks cb = j*4+wave.
// GEMM2:   h via LDS (half-split, aliases A), W2 global->reg ping-pong;
//          cross-wave LayerNorm reduction in LDS.
// Residual is bf16 (residB), output bf16 only (in-place safe).
// ---------------------------------------------------------------------------
struct MlpP {
    const u16* A1;
    const u16* A1b;
    const float* Araw;
    const int* src;
    const int* dsti;
    const u16* W1F;   // frag-major [K1/32][NH/16][64][8]
    const u16* W2F;   // frag-major [NH/32][NFRAG2][64][8]
    const float* b1;
    const float* b2;
    const float* g;
    const float* bt;
    const u16* residB;
    u16* outB;
    float* outDec;
};

template <int K1, int NH, int NOUT, int IN, int OUT, int A1S>
__global__ __launch_bounds__(256, 2) void mlp_kernel(MlpP p) {
    static_assert(K1 % 32 == 0 && NH % 128 == 0, "dims");
    constexpr int KSTEPS = K1 / 32;
    constexpr int KL = (K1 > 512) ? 512 : K1;    // cols staged in LDS
    constexpr int LSTEPS = KL / 32;
    constexpr int CH1 = KL / 8;                  // 16B chunks per A row
    constexpr int SWM = (CH1 % 8 == 0) ? 7 : 3;  // swizzle mask
    constexpr int NLOAD = (64 * CH1) / 256;
    constexpr int NT1 = NH / 64;                 // GEMM1 col-frags per wave
    constexpr int CB1 = NH / 16;
    constexpr int NFRAG2 = (NOUT + 15) / 16;
    constexpr int NT2 = (NFRAG2 + 3) / 4;        // GEMM2 frags per wave
    constexpr int S2 = NH / 64;                  // GEMM2 32-k steps per half
    constexpr int SH2 = NH / 2 + 8;              // padded h stride (u16)
    constexpr int HB = 64 * SH2 * 2;             // h bytes
    constexpr int A_B = 64 * KL * 2;             // A panel bytes
    constexpr int NEED = HB + 2560;
    constexpr int SMEM = (A_B > NEED) ? A_B : NEED;
    static_assert(SMEM <= 65536, "LDS per-WG limit");

    __shared__ __align__(16) char smem[SMEM];
    u16* sA = (u16*)smem;                        // [64][CH1 chunks] swizzled
    u16* sH = (u16*)smem;                        // [64][SH2] aliases sA
    float* sS1 = (float*)(smem + HB);            // [4][64]
    float* sS2 = sS1 + 256;                      // [4][64]
    float* sMu = sS1 + 512;                      // [64]
    float* sRs = sS1 + 576;                      // [64]

    const int tid = threadIdx.x;
    const int wave = tid >> 6, lane = tid & 63;
    const int lhi = lane >> 4, llo = lane & 15;
    const int r0 = blockIdx.x * 64;
    const int ko = lhi * 8;

    // ---------------- phase 0: stage A panel (one barrier) ----------------
    {
        #pragma unroll
        for (int i = 0; i < NLOAD; i++) {
            int s = tid + 256 * i;
            int r = s / CH1, c = s % CH1;
            uint4 v;
            if constexpr (IN == 0) {          // src(256) | dst(256)
                if (c < 32) v = *(const uint4*)(p.A1 + (size_t)p.src[r0 + r] * 256 + c * 8);
                else        v = *(const uint4*)(p.A1 + (size_t)p.dsti[r0 + r] * 256 + (c - 32) * 8);
            } else if constexpr (IN == 1) {   // node(256) | agg(128)
                if (c < 32) v = *(const uint4*)(p.A1 + (size_t)(r0 + r) * 256 + c * 8);
                else        v = *(const uint4*)(p.A1b + (size_t)(r0 + r) * 128 + (c - 32) * 8);
            } else if constexpr (IN == 2) {   // direct bf16, stride A1S
                v = *(const uint4*)(p.A1 + (size_t)(r0 + r) * A1S + c * 8);
            } else {                          // raw edge feats via perm (3 -> pad)
                uint4 t = {0u, 0u, 0u, 0u};
                if (c == 0) {
                    const float* q = p.Araw + (size_t)p.src[r0 + r] * 3;
                    t.x = pack2(q[0], q[1]);
                    t.y = pack2(q[2], 0.f);
                }
                v = t;
            }
            ((uint4*)sA)[r * CH1 + (c ^ (r & SWM))] = v;
        }
    }
    __syncthreads();

    // ---------------- GEMM1: barrier-free ---------------------------------
    auto readA = [&](int ks, bf16x8 (&d)[4]) {
        if (ks < LSTEPS) {
            #pragma unroll
            for (int m = 0; m < 4; m++) {
                int r = m * 16 + llo;
                d[m] = *(const bf16x8*)(sA + r * KL + ((ks * 4 + lhi) ^ (r & SWM)) * 8);
            }
        } else if constexpr (K1 > 512) {  // edge tail: contiguous rows
            #pragma unroll
            for (int m = 0; m < 4; m++)
                d[m] = *(const bf16x8*)(p.A1b + (size_t)(r0 + m * 16 + llo) * 128 +
                                        (ks * 32 - 512) + ko);
        }
    };
    auto loadB1 = [&](int ks, bf16x8 (&d)[NT1]) {
        #pragma unroll
        for (int j = 0; j < NT1; j++) {
            int cb = j * 4 + wave;
            d[j] = *(const bf16x8*)(p.W1F + ((size_t)(ks * CB1 + cb) * 64 + lane) * 8);
        }
    };

    const f32x4 fz = {0.f, 0.f, 0.f, 0.f};
    f32x4 acc[4][NT1];
    #pragma unroll
    for (int m = 0; m < 4; m++)
        #pragma unroll
        for (int j = 0; j < NT1; j++) acc[m][j] = fz;

    bf16x8 aA[4], aB[4];
    bf16x8 pb0[NT1], pb1[NT1];
    readA(0, aA);
    loadB1(0, pb0);
    if constexpr (KSTEPS > 1) loadB1(1, pb1);

    #pragma unroll
    for (int ks = 0; ks < KSTEPS; ks++) {
        bf16x8 (&cur)[4] = (ks & 1) ? aB : aA;
        bf16x8 (&nxt)[4] = (ks & 1) ? aA : aB;
        if (ks + 1 < KSTEPS) readA(ks + 1, nxt);
        bf16x8 (&pbc)[NT1] = (ks & 1) ? pb1 : pb0;
        #pragma unroll
        for (int j = 0; j < NT1; j++)
            #pragma unroll
            for (int m = 0; m < 4; m++) acc[m][j] = MFMA16(cur[m], pbc[j], acc[m][j]);
        if (ks + 2 < KSTEPS) loadB1(ks + 2, pbc);
    }
    __syncthreads();  // sH aliases sA

    // ---------------- phase 2: h halves -> LDS, GEMM2 ping-pong W2 --------
    f32x4 acc2[4][NT2];
    #pragma unroll
    for (int m = 0; m < 4; m++)
        #pragma unroll
        for (int j = 0; j < NT2; j++) acc2[m][j] = fz;

    auto loadW2 = [&](int g, bf16x8 (&d)[NT2]) {
        #pragma unroll
        for (int j = 0; j < NT2; j++) {
            int f = j * 4 + wave;
            if (NFRAG2 % 4 == 0 || f < NFRAG2)
                d[j] = *(const bf16x8*)(p.W2F + ((size_t)(g * NFRAG2 + f) * 64 + lane) * 8);
        }
    };
    bf16x8 pw0[NT2], pw1[NT2];
    loadW2(0, pw0);
    loadW2(1, pw1);

    #pragma unroll
    for (int half = 0; half < 2; half++) {
        // h-write: this wave's col-blocks of this half (SiLU via fast rcp)
        #pragma unroll
        for (int j = half * (NT1 / 2); j < (half + 1) * (NT1 / 2); j++) {
            int c = (j * 4 + wave) * 16 + llo;
            int coll = c - half * (NH / 2);
            float bias = p.b1[c];
            #pragma unroll
            for (int m = 0; m < 4; m++)
                #pragma unroll
                for (int r = 0; r < 4; r++) {
                    int row = m * 16 + lhi * 4 + r;
                    float v = acc[m][j][r] + bias;
                    float sgm = __builtin_amdgcn_rcpf(1.f + __expf(-v));
                    sH[row * SH2 + coll] = f2bf(v * sgm);
                }
        }
        __syncthreads();
        #pragma unroll
        for (int s = 0; s < S2; s++) {
            const int g = half * S2 + s;
            bf16x8 (&pwc)[NT2] = (g & 1) ? pw1 : pw0;
            bf16x8 a2[4];
            #pragma unroll
            for (int m = 0; m < 4; m++)
                a2[m] = *(const bf16x8*)(sH + (m * 16 + llo) * SH2 + s * 32 + lhi * 8);
            #pragma unroll
            for (int j = 0; j < NT2; j++)
                if (NFRAG2 % 4 == 0 || j * 4 + wave < NFRAG2)
                    #pragma unroll
                    for (int m = 0; m < 4; m++)
                        acc2[m][j] = MFMA16(a2[m], pwc[j], acc2[m][j]);
            if (g + 2 < 2 * S2) loadW2(g + 2, pwc);
        }
        __syncthreads();
    }

    // ---------------- epilogue ----------------
    if constexpr (OUT == 0) {  // +bias +resid(bf16), LayerNorm, bf16 out
        float ps1[4][4], ps2[4][4];
        #pragma unroll
        for (int m = 0; m < 4; m++)
            #pragma unroll
            for (int r = 0; r < 4; r++) { ps1[m][r] = 0.f; ps2[m][r] = 0.f; }
        #pragma unroll
        for (int j = 0; j < NT2; j++) {
            int col = (j * 4 + wave) * 16 + llo;
            float bias = p.b2[col];
            #pragma unroll
            for (int m = 0; m < 4; m++)
                #pragma unroll
                for (int r = 0; r < 4; r++) {
                    int row = m * 16 + lhi * 4 + r;
                    float v = acc2[m][j][r] + bias +
                              bf2f(p.residB[(size_t)(r0 + row) * NOUT + col]);
                    acc2[m][j][r] = v;
                    ps1[m][r] += v;
                    ps2[m][r] += v * v;
                }
        }
        #pragma unroll
        for (int mm = 1; mm < 16; mm <<= 1)
            #pragma unroll
            for (int m = 0; m < 4; m++)
                #pragma unroll
                for (int r = 0; r < 4; r++) {
                    ps1[m][r] += __shfl_xor(ps1[m][r], mm, 64);
                    ps2[m][r] += __shfl_xor(ps2[m][r], mm, 64);
                }
        if (llo == 0) {
            #pragma unroll
            for (int m = 0; m < 4; m++)
                #pragma unroll
                for (int r = 0; r < 4; r++) {
                    int row = m * 16 + lhi * 4 + r;
                    sS1[wave * 64 + row] = ps1[m][r];
                    sS2[wave * 64 + row] = ps2[m][r];
                }
        }
        __syncthreads();
        if (tid < 64) {
            float a = sS1[tid] + sS1[64 + tid] + sS1[128 + tid] + sS1[192 + tid];
            float b = sS2[tid] + sS2[64 + tid] + sS2[128 + tid] + sS2[192 + tid];
            float mu = a * (1.f / NOUT);
            float var = b * (1.f / NOUT) - mu * mu;
            sMu[tid] = mu;
            sRs[tid] = rsqrtf(var + 1e-5f);
        }
        __syncthreads();
        #pragma unroll
        for (int j = 0; j < NT2; j++) {
            int col = (j * 4 + wave) * 16 + llo;
            float gg = p.g[col], bb = p.bt[col];
            #pragma unroll
            for (int m = 0; m < 4; m++)
                #pragma unroll
                for (int r = 0; r < 4; r++) {
                    int row = m * 16 + lhi * 4 + r;
                    float v = (acc2[m][j][r] - sMu[row]) * sRs[row] * gg + bb;
                    p.outB[(size_t)(r0 + row) * NOUT + col] = f2bf(v);
                }
        }
    } else if constexpr (OUT == 1) {  // plain +bias, bf16 out
        #pragma unroll
        for (int j = 0; j < NT2; j++) {
            int col = (j * 4 + wave) * 16 + llo;
            float bias = p.b2[col];
            #pragma unroll
            for (int m = 0; m < 4; m++)
                #pragma unroll
                for (int r = 0; r < 4; r++) {
                    int row = m * 16 + lhi * 4 + r;
                    float v = acc2[m][j][r] + bias;
                    p.outB[(size_t)(r0 + row) * NOUT + col] = f2bf(v);
                }
        }
    } else {  // decoder: transposed fp32 store, ragged frags, cols < 69
        #pragma unroll
        for (int j = 0; j < NT2; j++) {
            int f = j * 4 + wave;
            int col = f * 16 + llo;
            if (f < NFRAG2 && col < 69) {
                float bias = p.b2[col];
                #pragma unroll
                for (int m = 0; m < 4; m++)
                    #pragma unroll
                    for (int r = 0; r < 4; r++) {
                        int row = m * 16 + lhi * 4 + r;
                        p.outDec[(size_t)col * NNODES + (r0 + row)] = acc2[m][j][r] + bias;
                    }
            }
        }
    }
}

// ---------------------------------------------------------------------------
extern "C" void kernel_launch(void* const* d_in, const int* in_sizes, int n_in,
                              void* d_out, int out_size, void* d_ws, size_t ws_size,
                              hipStream_t stream) {
    (void)in_sizes; (void)n_in; (void)out_size; (void)ws_size;

    const float* x       = (const float*)d_in[0];
    const int*   eidx    = (const int*)d_in[1];
    const float* raw_e   = (const float*)d_in[2];
    const float* enc_w1  = (const float*)d_in[3];
    const float* enc_b1  = (const float*)d_in[4];
    const float* enc_w2  = (const float*)d_in[5];
    const float* enc_b2  = (const float*)d_in[6];
    const float* eenc_w1 = (const float*)d_in[7];
    const float* eenc_b1 = (const float*)d_in[8];
    const float* eenc_w2 = (const float*)d_in[9];
    const float* eenc_b2 = (const float*)d_in[10];
    const float* pe_w1   = (const float*)d_in[11];
    const float* pe_b1   = (const float*)d_in[12];
    const float* pe_w2   = (const float*)d_in[13];
    const float* pe_b2   = (const float*)d_in[14];
    const float* pe_g    = (const float*)d_in[15];
    const float* pe_bt   = (const float*)d_in[16];
    const float* pn_w1   = (const float*)d_in[17];
    const float* pn_b1   = (const float*)d_in[18];
    const float* pn_w2   = (const float*)d_in[19];
    const float* pn_b2   = (const float*)d_in[20];
    const float* pn_g    = (const float*)d_in[21];
    const float* pn_bt   = (const float*)d_in[22];
    const float* dec_w1  = (const float*)d_in[23];
    const float* dec_b1  = (const float*)d_in[24];
    const float* dec_w2  = (const float*)d_in[25];
    const float* dec_b2  = (const float*)d_in[26];

    // ---- workspace carve ----
    char* ws = (char*)d_ws;
    size_t o = 0;
    auto alloc = [&](size_t bytes) -> void* {
        void* p = ws + o;
        o += (bytes + 255) & ~(size_t)255;
        return p;
    };
    u16*   node_b = (u16*)  alloc((size_t)NNODES * 256 * 2);
    u16*   edge_b = (u16*)  alloc((size_t)NEDGES * 128 * 2);   // sorted order
    u16*   aggB   = (u16*)  alloc((size_t)NNODES * 128 * 2);
    u16*   xT     = (u16*)  alloc((size_t)NNODES * 96 * 2);
    u16*   encw1F  = (u16*)alloc((size_t)96 * 256 * 2);
    u16*   encw2F  = (u16*)alloc((size_t)256 * 256 * 2);
    u16*   eencw1F = (u16*)alloc((size_t)32 * 128 * 2);
    u16*   eencw2F = (u16*)alloc((size_t)128 * 128 * 2);
    u16*   pew1F   = (u16*)alloc((size_t)8 * 640 * 512 * 2);
    u16*   pew2F   = (u16*)alloc((size_t)8 * 512 * 128 * 2);
    u16*   pnw1F   = (u16*)alloc((size_t)8 * 384 * 512 * 2);
    u16*   pnw2F   = (u16*)alloc((size_t)8 * 512 * 256 * 2);
    u16*   decw1F  = (u16*)alloc((size_t)256 * 256 * 2);
    u16*   decw2F  = (u16*)alloc((size_t)256 * 80 * 2);
    int*   sd     = (int*)  alloc((size_t)2 * NEDGES * 4);
    int*   deg    = (int*)  alloc((size_t)NNODES * 4);
    int*   off_   = (int*)  alloc((size_t)(NNODES + 1) * 4);
    int*   cur    = (int*)  alloc((size_t)NNODES * 4);
    int*   perm   = (int*)  alloc((size_t)NEDGES * 4);
    int*   srcS   = (int*)  alloc((size_t)NEDGES * 4);
    int*   dstS   = (int*)  alloc((size_t)NEDGES * 4);

    // ---- weight prep: fragment-major pack ----
    auto FP = [&](const float* W, u16* F, int K, int N, int KB, int CB, int batch) {
        int nf = KB * CB;
        dim3 g((nf + 3) / 4, 1, batch);
        fragpack_kernel<<<g, 256, 0, stream>>>(W, F, K, N, CB, nf);
    };
    FP(enc_w1,  encw1F,  70,  256, 3,  16, 1);
    FP(enc_w2,  encw2F,  256, 256, 8,  16, 1);
    FP(eenc_w1, eencw1F, 3,   128, 1,  8,  1);
    FP(eenc_w2, eencw2F, 128, 128, 4,  8,  1);
    FP(pe_w1,   pew1F,   640, 512, 20, 32, 8);
    FP(pe_w2,   pew2F,   512, 128, 16, 8,  8);
    FP(pn_w1,   pnw1F,   384, 512, 12, 32, 8);
    FP(pn_w2,   pnw2F,   512, 256, 16, 16, 8);
    FP(dec_w1,  decw1F,  256, 256, 8,  16, 1);
    FP(dec_w2,  decw2F,  256, 69,  8,  5,  1);
    {   // x (70, N) -> xT (N, 96) bf16
        dim3 g(96 / 32, NNODES / 32, 1);
        wtrans_kernel<<<g, 256, 0, stream>>>(x, xT, 70, NNODES, 96, NNODES);
    }

    // ---- indices + CSR + edge sort ----
    idx_norm_kernel<<<1536, 256, 0, stream>>>(eidx, sd);
    hipMemsetAsync(deg, 0, (size_t)NNODES * 4, stream);
    csr_count_kernel<<<NEDGES / 256, 256, 0, stream>>>(sd + NEDGES, deg);
    csr_scan_kernel<<<1, 1024, 0, stream>>>(deg, off_, cur);
    csr_fill_kernel<<<NEDGES / 256, 256, 0, stream>>>(sd + NEDGES, cur, perm);
    esort_kernel<<<NEDGES / 256, 256, 0, stream>>>(sd, perm, srcS, dstS);

    // ---- encoders ----
    {
        MlpP p{};
        p.A1 = xT; p.W1F = encw1F; p.W2F = encw2F; p.b1 = enc_b1; p.b2 = enc_b2;
        p.outB = node_b;
        mlp_kernel<96, 256, 256, 2, 1, 96><<<NNODES / 64, 256, 0, stream>>>(p);
    }
    {   // edge encoder: reads raw feats via perm, writes sorted order
        MlpP p{};
        p.Araw = raw_e; p.src = perm;
        p.W1F = eencw1F; p.W2F = eencw2F; p.b1 = eenc_b1; p.b2 = eenc_b2;
        p.outB = edge_b;
        mlp_kernel<32, 128, 128, 3, 1, 0><<<NEDGES / 64, 256, 0, stream>>>(p);
    }

    // ---- processor layers ----
    for (int l = 0; l < 8; l++) {
        {
            MlpP p{};
            p.A1 = node_b; p.A1b = edge_b; p.src = srcS; p.dsti = dstS;
            p.W1F = pew1F + (size_t)l * 640 * 512;
            p.W2F = pew2F + (size_t)l * 512 * 128;
            p.b1 = pe_b1 + l * 512; p.b2 = pe_b2 + l * 128;
            p.g = pe_g + l * 128; p.bt = pe_bt + l * 128;
            p.residB = edge_b; p.outB = edge_b;   // in-place (own rows only)
            mlp_kernel<640, 512, 128, 0, 0, 0><<<NEDGES / 64, 256, 0, stream>>>(p);
        }
        gather_kernel<<<NNODES * 32 / 256, 256, 0, stream>>>(edge_b, off_, aggB);
        {
            MlpP p{};
            p.A1 = node_b; p.A1b = aggB;
            p.W1F = pnw1F + (size_t)l * 384 * 512;
            p.W2F = pnw2F + (size_t)l * 512 * 256;
            p.b1 = pn_b1 + l * 512; p.b2 = pn_b2 + l * 256;
            p.g = pn_g + l * 256; p.bt = pn_bt + l * 256;
            p.residB = node_b; p.outB = node_b;   // in-place (own rows only)
            mlp_kernel<384, 512, 256, 1, 0, 0><<<NNODES / 64, 256, 0, stream>>>(p);
        }
    }

    // ---- decoder ----
    {
        MlpP p{};
        p.A1 = node_b; p.W1F = decw1F; p.W2F = decw2F; p.b1 = dec_b1; p.b2 = dec_b2;
        p.outDec = (float*)d_out;
        mlp_kernel<256, 256, 80, 2, 2, 256><<<NNODES / 64, 256, 0, stream>>>(p);
    }
}

// Round 7
// 2408.781 us; speedup vs baseline: 1.4997x; 1.3680x over previous
//
#include <hip/hip_runtime.h>

// ---------------------------------------------------------------------------
// GraphCast-style GNN on MI355X (gfx950). Round 7:
//  - A panel staged to LDS once (XOR-swizzled), GEMM1 barrier-free:
//    A frags ds_read ping-pong (32 VGPR), B frags SINGLE-buffer JIT reload
//    (32 VGPR) -- round-6's double ping-pong spilled ~550B/thread.
//  - full-width swizzled h in LDS: acc (128 AGPR) fully drained before
//    GEMM2 starts -> no acc/acc2 co-live register cliff, one fewer barrier.
//  - bf16 residual in-place; LN scratch aliases smem (h dead by then).
// ---------------------------------------------------------------------------

typedef __attribute__((ext_vector_type(8))) short bf16x8;
typedef __attribute__((ext_vector_type(4))) float f32x4;
typedef unsigned short u16;

#define NNODES 32768
#define NEDGES 196608

#define MFMA16(a, b, c) __builtin_amdgcn_mfma_f32_16x16x32_bf16((a), (b), (c), 0, 0, 0)

__device__ __forceinline__ u16 f2bf(float f) {
    unsigned u = __float_as_uint(f);
    unsigned r = (u + 0x7FFFu + ((u >> 16) & 1u)) >> 16;  // RNE
    return (u16)r;
}
__device__ __forceinline__ float bf2f(u16 b) {
    return __uint_as_float(((unsigned)b) << 16);
}
__device__ __forceinline__ unsigned pack2(float a, float b) {
    return (unsigned)f2bf(a) | ((unsigned)f2bf(b) << 16);
}

// ---------------------------------------------------------------------------
// Input transpose (x only): W (K, Nout) fp32 -> WT (NP, Kpad) bf16
// ---------------------------------------------------------------------------
__global__ void wtrans_kernel(const float* __restrict__ W, u16* __restrict__ WT,
                              int K, int Nout, int Kpad, int NP) {
    __shared__ u16 tile[32][33];
    const int k0 = blockIdx.x * 32, n0 = blockIdx.y * 32;
    const int tx = threadIdx.x & 31, ty = threadIdx.x >> 5;  // 32 x 8
    #pragma unroll
    for (int i = 0; i < 4; i++) {
        int k = k0 + ty + 8 * i, n = n0 + tx;
        float v = (k < K && n < Nout) ? W[(size_t)k * Nout + n] : 0.f;
        tile[ty + 8 * i][tx] = f2bf(v);
    }
    __syncthreads();
    #pragma unroll
    for (int i = 0; i < 4; i++) {
        int n = n0 + ty + 8 * i, k = k0 + tx;
        if (n < NP && k < Kpad) WT[(size_t)n * Kpad + k] = tile[tx][ty + 8 * i];
    }
}

// ---------------------------------------------------------------------------
// Fragment-major weight pack: W (batch, K, N) fp32 -> frags bf16.
// Frag (ks, cb): lane l, elem j  <-  W[k = ks*32 + (l>>4)*8 + j][n = cb*16 + (l&15)]
// ---------------------------------------------------------------------------
__global__ void fragpack_kernel(const float* __restrict__ W, u16* __restrict__ F,
                                int K, int N, int CB, int NFRAG) {
    int b = blockIdx.z;
    int fr = blockIdx.x * 4 + (threadIdx.x >> 6);
    if (fr >= NFRAG) return;
    int l = threadIdx.x & 63;
    int ks = fr / CB, cb = fr % CB;
    int k0 = ks * 32 + ((l >> 4) * 8);
    int n = cb * 16 + (l & 15);
    u16 v[8];
    #pragma unroll
    for (int j = 0; j < 8; j++) {
        int k = k0 + j;
        float x = (k < K && n < N) ? W[((size_t)b * K + k) * N + n] : 0.f;
        v[j] = f2bf(x);
    }
    *(uint4*)(F + (((size_t)b * NFRAG + fr) * 64 + l) * 8) = *(const uint4*)v;
}

// ---------------------------------------------------------------------------
// edge_index normalization (int64 payload -> int32 [src | dst])
// ---------------------------------------------------------------------------
__global__ void idx_norm_kernel(const int* __restrict__ raw, int* __restrict__ sd) {
    __shared__ int nz;
    if (threadIdx.x == 0) nz = 0;
    __syncthreads();
    for (int i = threadIdx.x; i < 512; i += 256)
        if (raw[2 * i + 1] != 0) atomicAdd(&nz, 1);
    __syncthreads();
    const bool is64 = (nz == 0);
    int idx = blockIdx.x * 256 + threadIdx.x;
    if (idx < 2 * NEDGES) sd[idx] = is64 ? raw[2 * idx] : raw[idx];
}

// ---------------------------------------------------------------------------
// CSR build (by dst) + edge sort.
// ---------------------------------------------------------------------------
__global__ void csr_count_kernel(const int* __restrict__ dsti, int* __restrict__ deg) {
    int e = blockIdx.x * 256 + threadIdx.x;
    atomicAdd(&deg[dsti[e]], 1);
}

__global__ void csr_scan_kernel(const int* __restrict__ deg, int* __restrict__ off,
                                int* __restrict__ cur) {
    __shared__ int part[1024];
    const int t = threadIdx.x;
    int local[32];
    int s = 0;
    #pragma unroll
    for (int i = 0; i < 32; i++) { local[i] = deg[t * 32 + i]; s += local[i]; }
    part[t] = s;
    __syncthreads();
    for (int d = 1; d < 1024; d <<= 1) {
        int v = (t >= d) ? part[t - d] : 0;
        __syncthreads();
        part[t] += v;
        __syncthreads();
    }
    int excl = (t == 0) ? 0 : part[t - 1];
    #pragma unroll
    for (int i = 0; i < 32; i++) {
        off[t * 32 + i] = excl;
        cur[t * 32 + i] = excl;
        excl += local[i];
    }
    if (t == 1023) off[NNODES] = excl;
}

__global__ void csr_fill_kernel(const int* __restrict__ dsti, int* __restrict__ cur,
                                int* __restrict__ perm) {
    int e = blockIdx.x * 256 + threadIdx.x;
    int pos = atomicAdd(&cur[dsti[e]], 1);
    perm[pos] = e;
}

// sorted-order src/dst arrays
__global__ void esort_kernel(const int* __restrict__ sd, const int* __restrict__ perm,
                             int* __restrict__ srcS, int* __restrict__ dstS) {
    int i = blockIdx.x * 256 + threadIdx.x;
    int e = perm[i];
    srcS[i] = sd[e];
    dstS[i] = sd[NEDGES + e];
}

// aggB[n][c] = sum over sorted edge rows off[n]..off[n+1] of edge_b[i][c]
__global__ void gather_kernel(const u16* __restrict__ edge_b,
                              const int* __restrict__ off, u16* __restrict__ aggB) {
    int idx = blockIdx.x * 256 + threadIdx.x;  // N*32 threads
    int n = idx >> 5, c = (idx & 31) * 4;
    int a = off[n], b = off[n + 1];
    float s0 = 0.f, s1 = 0.f, s2 = 0.f, s3 = 0.f;
    for (int i = a; i < b; i++) {
        uint2 v = *(const uint2*)(edge_b + (size_t)i * 128 + c);
        s0 += bf2f((u16)(v.x & 0xffff)); s1 += bf2f((u16)(v.x >> 16));
        s2 += bf2f((u16)(v.y & 0xffff)); s3 += bf2f((u16)(v.y >> 16));
    }
    uint2 o;
    o.x = pack2(s0, s1);
    o.y = pack2(s2, s3);
    *(uint2*)(aggB + (size_t)n * 128 + c) = o;
}

// ---------------------------------------------------------------------------
// Fused 2-layer MLP.  Block = 256 threads (4 waves) = 64 rows.
// Phase 0: stage A panel (K<=512) into LDS once (XOR-swizzled 16B chunks).
// GEMM1:   barrier-free; A frags ds_read ping-pong, B frags single-buffer
//          JIT reload. Edge tail (K>=512) per-lane direct (contiguous rows).
// h:       one phase: SiLU(acc)+b1 -> full-width swizzled sH; acc dies here.
// GEMM2:   barrier-free over sH; W2 global->reg ping-pong; LN via LDS.
// ---------------------------------------------------------------------------
struct MlpP {
    const u16* A1;
    const u16* A1b;
    const float* Araw;
    const int* src;
    const int* dsti;
    const u16* W1F;   // frag-major [K1/32][NH/16][64][8]
    const u16* W2F;   // frag-major [NH/32][NFRAG2][64][8]
    const float* b1;
    const float* b2;
    const float* g;
    const float* bt;
    const u16* residB;
    u16* outB;
    float* outDec;
};

template <int K1, int NH, int NOUT, int IN, int OUT, int A1S>
__global__ __launch_bounds__(256, 2) void mlp_kernel(MlpP p) {
    static_assert(K1 % 32 == 0 && NH % 128 == 0, "dims");
    constexpr int KSTEPS = K1 / 32;
    constexpr int KL = (K1 > 512) ? 512 : K1;    // cols staged in LDS
    constexpr int LSTEPS = KL / 32;
    constexpr int CH1 = KL / 8;                  // 16B chunks per A row
    constexpr int SWM = (CH1 % 8 == 0) ? 7 : 3;  // A-panel swizzle mask
    constexpr int NLOAD = (64 * CH1) / 256;
    constexpr int NT1 = NH / 64;                 // GEMM1 col-frags per wave
    constexpr int CB1 = NH / 16;
    constexpr int NFRAG2 = (NOUT + 15) / 16;
    constexpr int NT2 = (NFRAG2 + 3) / 4;        // GEMM2 frags per wave
    constexpr int S2T = NH / 32;                 // GEMM2 32-k steps (full)
    constexpr int HB = 64 * NH * 2;              // h bytes (stride NH, swizzled)
    constexpr int A_B = 64 * KL * 2;             // A panel bytes
    constexpr int SMEM = (A_B > HB) ? A_B : HB;
    static_assert(SMEM <= 65536, "LDS per-WG limit");

    __shared__ __align__(16) char smem[SMEM];
    u16* sA = (u16*)smem;                        // [64][CH1 chunks] swizzled
    u16* sH = (u16*)smem;                        // [64][NH] swizzled, aliases sA
    float* sS1 = (float*)smem;                   // LN scratch (h dead by then)
    float* sS2 = sS1 + 256;
    float* sMu = sS1 + 512;
    float* sRs = sS1 + 576;

    const int tid = threadIdx.x;
    const int wave = tid >> 6, lane = tid & 63;
    const int lhi = lane >> 4, llo = lane & 15;
    const int r0 = blockIdx.x * 64;
    const int ko = lhi * 8;

    // ---------------- phase 0: stage A panel (one barrier) ----------------
    {
        #pragma unroll
        for (int i = 0; i < NLOAD; i++) {
            int s = tid + 256 * i;
            int r = s / CH1, c = s % CH1;
            uint4 v;
            if constexpr (IN == 0) {          // src(256) | dst(256)
                if (c < 32) v = *(const uint4*)(p.A1 + (size_t)p.src[r0 + r] * 256 + c * 8);
                else        v = *(const uint4*)(p.A1 + (size_t)p.dsti[r0 + r] * 256 + (c - 32) * 8);
            } else if constexpr (IN == 1) {   // node(256) | agg(128)
                if (c < 32) v = *(const uint4*)(p.A1 + (size_t)(r0 + r) * 256 + c * 8);
                else        v = *(const uint4*)(p.A1b + (size_t)(r0 + r) * 128 + (c - 32) * 8);
            } else if constexpr (IN == 2) {   // direct bf16, stride A1S
                v = *(const uint4*)(p.A1 + (size_t)(r0 + r) * A1S + c * 8);
            } else {                          // raw edge feats via perm (3 -> pad)
                uint4 t = {0u, 0u, 0u, 0u};
                if (c == 0) {
                    const float* q = p.Araw + (size_t)p.src[r0 + r] * 3;
                    t.x = pack2(q[0], q[1]);
                    t.y = pack2(q[2], 0.f);
                }
                v = t;
            }
            ((uint4*)sA)[r * CH1 + (c ^ (r & SWM))] = v;
        }
    }
    __syncthreads();

    // ---------------- GEMM1: barrier-free ---------------------------------
    auto readA = [&](int ks, bf16x8 (&d)[4]) {
        if (ks < LSTEPS) {
            #pragma unroll
            for (int m = 0; m < 4; m++) {
                int r = m * 16 + llo;
                d[m] = *(const bf16x8*)(sA + r * KL + (((ks * 4 + lhi) ^ (r & SWM)) * 8));
            }
        } else if constexpr (K1 > 512) {  // edge tail: contiguous rows
            #pragma unroll
            for (int m = 0; m < 4; m++)
                d[m] = *(const bf16x8*)(p.A1b + (size_t)(r0 + m * 16 + llo) * 128 +
                                        (ks * 32 - 512) + ko);
        }
    };
    auto loadB1frag = [&](int ks, int j) -> bf16x8 {
        int cb = j * 4 + wave;
        return *(const bf16x8*)(p.W1F + ((size_t)(ks * CB1 + cb) * 64 + lane) * 8);
    };

    const f32x4 fz = {0.f, 0.f, 0.f, 0.f};
    f32x4 acc[4][NT1];
    #pragma unroll
    for (int m = 0; m < 4; m++)
        #pragma unroll
        for (int j = 0; j < NT1; j++) acc[m][j] = fz;

    bf16x8 aA[4], aB[4];
    bf16x8 pb[NT1];
    readA(0, aA);
    #pragma unroll
    for (int j = 0; j < NT1; j++) pb[j] = loadB1frag(0, j);

    #pragma unroll
    for (int ks = 0; ks < KSTEPS; ks++) {
        bf16x8 (&cur)[4] = (ks & 1) ? aB : aA;
        bf16x8 (&nxt)[4] = (ks & 1) ? aA : aB;
        if (ks + 1 < KSTEPS) readA(ks + 1, nxt);  // dist-1 A prefetch
        #pragma unroll
        for (int j = 0; j < NT1; j++) {
            #pragma unroll
            for (int m = 0; m < 4; m++) acc[m][j] = MFMA16(cur[m], pb[j], acc[m][j]);
            if (ks + 1 < KSTEPS) pb[j] = loadB1frag(ks + 1, j);  // JIT reload
        }
    }
    __syncthreads();  // sH aliases sA

    // ---------------- h: SiLU(acc + b1) -> full-width swizzled sH ---------
    #pragma unroll
    for (int j = 0; j < NT1; j++) {
        int c = (j * 4 + wave) * 16 + llo;
        float bias = p.b1[c];
        int cs_hi = c >> 3, cs_lo = c & 7;
        #pragma unroll
        for (int m = 0; m < 4; m++)
            #pragma unroll
            for (int r = 0; r < 4; r++) {
                int row = m * 16 + lhi * 4 + r;
                float v = acc[m][j][r] + bias;
                float sgm = __builtin_amdgcn_rcpf(1.f + __expf(-v));
                sH[row * NH + ((cs_hi ^ (row & 7)) * 8 + cs_lo)] = f2bf(v * sgm);
            }
    }
    __syncthreads();

    // ---------------- GEMM2: barrier-free over sH, W2 ping-pong -----------
    f32x4 acc2[4][NT2];
    #pragma unroll
    for (int m = 0; m < 4; m++)
        #pragma unroll
        for (int j = 0; j < NT2; j++) acc2[m][j] = fz;

    auto loadW2 = [&](int g, bf16x8 (&d)[NT2]) {
        #pragma unroll
        for (int j = 0; j < NT2; j++) {
            int f = j * 4 + wave;
            if (NFRAG2 % 4 == 0 || f < NFRAG2)
                d[j] = *(const bf16x8*)(p.W2F + ((size_t)(g * NFRAG2 + f) * 64 + lane) * 8);
        }
    };
    bf16x8 pw0[NT2], pw1[NT2];
    loadW2(0, pw0);
    if constexpr (S2T > 1) loadW2(1, pw1);

    #pragma unroll
    for (int s = 0; s < S2T; s++) {
        bf16x8 (&pwc)[NT2] = (s & 1) ? pw1 : pw0;
        bf16x8 a2[4];
        #pragma unroll
        for (int m = 0; m < 4; m++) {
            int row = m * 16 + llo;
            a2[m] = *(const bf16x8*)(sH + row * NH + (((s * 4 + lhi) ^ (row & 7)) * 8));
        }
        #pragma unroll
        for (int j = 0; j < NT2; j++)
            if (NFRAG2 % 4 == 0 || j * 4 + wave < NFRAG2)
                #pragma unroll
                for (int m = 0; m < 4; m++)
                    acc2[m][j] = MFMA16(a2[m], pwc[j], acc2[m][j]);
        if (s + 2 < S2T) loadW2(s + 2, pwc);
    }
    __syncthreads();  // LN scratch aliases sH

    // ---------------- epilogue ----------------
    if constexpr (OUT == 0) {  // +bias +resid(bf16), LayerNorm, bf16 out
        float ps1[4][4], ps2[4][4];
        #pragma unroll
        for (int m = 0; m < 4; m++)
            #pragma unroll
            for (int r = 0; r < 4; r++) { ps1[m][r] = 0.f; ps2[m][r] = 0.f; }
        #pragma unroll
        for (int j = 0; j < NT2; j++) {
            int col = (j * 4 + wave) * 16 + llo;
            float bias = p.b2[col];
            #pragma unroll
            for (int m = 0; m < 4; m++)
                #pragma unroll
                for (int r = 0; r < 4; r++) {
                    int row = m * 16 + lhi * 4 + r;
                    float v = acc2[m][j][r] + bias +
                              bf2f(p.residB[(size_t)(r0 + row) * NOUT + col]);
                    acc2[m][j][r] = v;
                    ps1[m][r] += v;
                    ps2[m][r] += v * v;
                }
        }
        #pragma unroll
        for (int mm = 1; mm < 16; mm <<= 1)
            #pragma unroll
            for (int m = 0; m < 4; m++)
                #pragma unroll
                for (int r = 0; r < 4; r++) {
                    ps1[m][r] += __shfl_xor(ps1[m][r], mm, 64);
                    ps2[m][r] += __shfl_xor(ps2[m][r], mm, 64);
                }
        if (llo == 0) {
            #pragma unroll
            for (int m = 0; m < 4; m++)
                #pragma unroll
                for (int r = 0; r < 4; r++) {
                    int row = m * 16 + lhi * 4 + r;
                    sS1[wave * 64 + row] = ps1[m][r];
                    sS2[wave * 64 + row] = ps2[m][r];
                }
        }
        __syncthreads();
        if (tid < 64) {
            float a = sS1[tid] + sS1[64 + tid] + sS1[128 + tid] + sS1[192 + tid];
            float b = sS2[tid] + sS2[64 + tid] + sS2[128 + tid] + sS2[192 + tid];
            float mu = a * (1.f / NOUT);
            float var = b * (1.f / NOUT) - mu * mu;
            sMu[tid] = mu;
            sRs[tid] = rsqrtf(var + 1e-5f);
        }
        __syncthreads();
        #pragma unroll
        for (int j = 0; j < NT2; j++) {
            int col = (j * 4 + wave) * 16 + llo;
            float gg = p.g[col], bb = p.bt[col];
            #pragma unroll
            for (int m = 0; m < 4; m++)
                #pragma unroll
                for (int r = 0; r < 4; r++) {
                    int row = m * 16 + lhi * 4 + r;
                    float v = (acc2[m][j][r] - sMu[row]) * sRs[row] * gg + bb;
                    p.outB[(size_t)(r0 + row) * NOUT + col] = f2bf(v);
                }
        }
    } else if constexpr (OUT == 1) {  // plain +bias, bf16 out
        #pragma unroll
        for (int j = 0; j < NT2; j++) {
            int col = (j * 4 + wave) * 16 + llo;
            float bias = p.b2[col];
            #pragma unroll
            for (int m = 0; m < 4; m++)
                #pragma unroll
                for (int r = 0; r < 4; r++) {
                    int row = m * 16 + lhi * 4 + r;
                    float v = acc2[m][j][r] + bias;
                    p.outB[(size_t)(r0 + row) * NOUT + col] = f2bf(v);
                }
        }
    } else {  // decoder: transposed fp32 store, ragged frags, cols < 69
        #pragma unroll
        for (int j = 0; j < NT2; j++) {
            int f = j * 4 + wave;
            int col = f * 16 + llo;
            if (f < NFRAG2 && col < 69) {
                float bias = p.b2[col];
                #pragma unroll
                for (int m = 0; m < 4; m++)
                    #pragma unroll
                    for (int r = 0; r < 4; r++) {
                        int row = m * 16 + lhi * 4 + r;
                        p.outDec[(size_t)col * NNODES + (r0 + row)] = acc2[m][j][r] + bias;
                    }
            }
        }
    }
}

// ---------------------------------------------------------------------------
extern "C" void kernel_launch(void* const* d_in, const int* in_sizes, int n_in,
                              void* d_out, int out_size, void* d_ws, size_t ws_size,
                              hipStream_t stream) {
    (void)in_sizes; (void)n_in; (void)out_size; (void)ws_size;

    const float* x       = (const float*)d_in[0];
    const int*   eidx    = (const int*)d_in[1];
    const float* raw_e   = (const float*)d_in[2];
    const float* enc_w1  = (const float*)d_in[3];
    const float* enc_b1  = (const float*)d_in[4];
    const float* enc_w2  = (const float*)d_in[5];
    const float* enc_b2  = (const float*)d_in[6];
    const float* eenc_w1 = (const float*)d_in[7];
    const float* eenc_b1 = (const float*)d_in[8];
    const float* eenc_w2 = (const float*)d_in[9];
    const float* eenc_b2 = (const float*)d_in[10];
    const float* pe_w1   = (const float*)d_in[11];
    const float* pe_b1   = (const float*)d_in[12];
    const float* pe_w2   = (const float*)d_in[13];
    const float* pe_b2   = (const float*)d_in[14];
    const float* pe_g    = (const float*)d_in[15];
    const float* pe_bt   = (const float*)d_in[16];
    const float* pn_w1   = (const float*)d_in[17];
    const float* pn_b1   = (const float*)d_in[18];
    const float* pn_w2   = (const float*)d_in[19];
    const float* pn_b2   = (const float*)d_in[20];
    const float* pn_g    = (const float*)d_in[21];
    const float* pn_bt   = (const float*)d_in[22];
    const float* dec_w1  = (const float*)d_in[23];
    const float* dec_b1  = (const float*)d_in[24];
    const float* dec_w2  = (const float*)d_in[25];
    const float* dec_b2  = (const float*)d_in[26];

    // ---- workspace carve ----
    char* ws = (char*)d_ws;
    size_t o = 0;
    auto alloc = [&](size_t bytes) -> void* {
        void* p = ws + o;
        o += (bytes + 255) & ~(size_t)255;
        return p;
    };
    u16*   node_b = (u16*)  alloc((size_t)NNODES * 256 * 2);
    u16*   edge_b = (u16*)  alloc((size_t)NEDGES * 128 * 2);   // sorted order
    u16*   aggB   = (u16*)  alloc((size_t)NNODES * 128 * 2);
    u16*   xT     = (u16*)  alloc((size_t)NNODES * 96 * 2);
    u16*   encw1F  = (u16*)alloc((size_t)96 * 256 * 2);
    u16*   encw2F  = (u16*)alloc((size_t)256 * 256 * 2);
    u16*   eencw1F = (u16*)alloc((size_t)32 * 128 * 2);
    u16*   eencw2F = (u16*)alloc((size_t)128 * 128 * 2);
    u16*   pew1F   = (u16*)alloc((size_t)8 * 640 * 512 * 2);
    u16*   pew2F   = (u16*)alloc((size_t)8 * 512 * 128 * 2);
    u16*   pnw1F   = (u16*)alloc((size_t)8 * 384 * 512 * 2);
    u16*   pnw2F   = (u16*)alloc((size_t)8 * 512 * 256 * 2);
    u16*   decw1F  = (u16*)alloc((size_t)256 * 256 * 2);
    u16*   decw2F  = (u16*)alloc((size_t)256 * 80 * 2);
    int*   sd     = (int*)  alloc((size_t)2 * NEDGES * 4);
    int*   deg    = (int*)  alloc((size_t)NNODES * 4);
    int*   off_   = (int*)  alloc((size_t)(NNODES + 1) * 4);
    int*   cur    = (int*)  alloc((size_t)NNODES * 4);
    int*   perm   = (int*)  alloc((size_t)NEDGES * 4);
    int*   srcS   = (int*)  alloc((size_t)NEDGES * 4);
    int*   dstS   = (int*)  alloc((size_t)NEDGES * 4);

    // ---- weight prep: fragment-major pack ----
    auto FP = [&](const float* W, u16* F, int K, int N, int KB, int CB, int batch) {
        int nf = KB * CB;
        dim3 g((nf + 3) / 4, 1, batch);
        fragpack_kernel<<<g, 256, 0, stream>>>(W, F, K, N, CB, nf);
    };
    FP(enc_w1,  encw1F,  70,  256, 3,  16, 1);
    FP(enc_w2,  encw2F,  256, 256, 8,  16, 1);
    FP(eenc_w1, eencw1F, 3,   128, 1,  8,  1);
    FP(eenc_w2, eencw2F, 128, 128, 4,  8,  1);
    FP(pe_w1,   pew1F,   640, 512, 20, 32, 8);
    FP(pe_w2,   pew2F,   512, 128, 16, 8,  8);
    FP(pn_w1,   pnw1F,   384, 512, 12, 32, 8);
    FP(pn_w2,   pnw2F,   512, 256, 16, 16, 8);
    FP(dec_w1,  decw1F,  256, 256, 8,  16, 1);
    FP(dec_w2,  decw2F,  256, 69,  8,  5,  1);
    {   // x (70, N) -> xT (N, 96) bf16
        dim3 g(96 / 32, NNODES / 32, 1);
        wtrans_kernel<<<g, 256, 0, stream>>>(x, xT, 70, NNODES, 96, NNODES);
    }

    // ---- indices + CSR + edge sort ----
    idx_norm_kernel<<<1536, 256, 0, stream>>>(eidx, sd);
    hipMemsetAsync(deg, 0, (size_t)NNODES * 4, stream);
    csr_count_kernel<<<NEDGES / 256, 256, 0, stream>>>(sd + NEDGES, deg);
    csr_scan_kernel<<<1, 1024, 0, stream>>>(deg, off_, cur);
    csr_fill_kernel<<<NEDGES / 256, 256, 0, stream>>>(sd + NEDGES, cur, perm);
    esort_kernel<<<NEDGES / 256, 256, 0, stream>>>(sd, perm, srcS, dstS);

    // ---- encoders ----
    {
        MlpP p{};
        p.A1 = xT; p.W1F = encw1F; p.W2F = encw2F; p.b1 = enc_b1; p.b2 = enc_b2;
        p.outB = node_b;
        mlp_kernel<96, 256, 256, 2, 1, 96><<<NNODES / 64, 256, 0, stream>>>(p);
    }
    {   // edge encoder: reads raw feats via perm, writes sorted order
        MlpP p{};
        p.Araw = raw_e; p.src = perm;
        p.W1F = eencw1F; p.W2F = eencw2F; p.b1 = eenc_b1; p.b2 = eenc_b2;
        p.outB = edge_b;
        mlp_kernel<32, 128, 128, 3, 1, 0><<<NEDGES / 64, 256, 0, stream>>>(p);
    }

    // ---- processor layers ----
    for (int l = 0; l < 8; l++) {
        {
            MlpP p{};
            p.A1 = node_b; p.A1b = edge_b; p.src = srcS; p.dsti = dstS;
            p.W1F = pew1F + (size_t)l * 640 * 512;
            p.W2F = pew2F + (size_t)l * 512 * 128;
            p.b1 = pe_b1 + l * 512; p.b2 = pe_b2 + l * 128;
            p.g = pe_g + l * 128; p.bt = pe_bt + l * 128;
            p.residB = edge_b; p.outB = edge_b;   // in-place (own rows only)
            mlp_kernel<640, 512, 128, 0, 0, 0><<<NEDGES / 64, 256, 0, stream>>>(p);
        }
        gather_kernel<<<NNODES * 32 / 256, 256, 0, stream>>>(edge_b, off_, aggB);
        {
            MlpP p{};
            p.A1 = node_b; p.A1b = aggB;
            p.W1F = pnw1F + (size_t)l * 384 * 512;
            p.W2F = pnw2F + (size_t)l * 512 * 256;
            p.b1 = pn_b1 + l * 512; p.b2 = pn_b2 + l * 256;
            p.g = pn_g + l * 256; p.bt = pn_bt + l * 256;
            p.residB = node_b; p.outB = node_b;   // in-place (own rows only)
            mlp_kernel<384, 512, 256, 1, 0, 0><<<NNODES / 64, 256, 0, stream>>>(p);
        }
    }

    // ---- decoder ----
    {
        MlpP p{};
        p.A1 = node_b; p.W1F = decw1F; p.W2F = decw2F; p.b1 = dec_b1; p.b2 = dec_b2;
        p.outDec = (float*)d_out;
        mlp_kernel<256, 256, 80, 2, 2, 256><<<NNODES / 64, 256, 0, stream>>>(p);
    }
}

// Round 8
// 2042.951 us; speedup vs baseline: 1.7683x; 1.1791x over previous
//
#include <hip/hip_runtime.h>

// ---------------------------------------------------------------------------
// GraphCast-style GNN on MI355X (gfx950). Round 8 = round-4 structure
// (best pipeline: per-step LDS A-tile dbuf, 1 barrier/step, A ring-3,
// B frag ping-pong dist-2) + round-7 data plan (bf16 residual in-place,
// bf16 agg, sorted edges, single bf16 store).
// ---------------------------------------------------------------------------

typedef __attribute__((ext_vector_type(8))) short bf16x8;
typedef __attribute__((ext_vector_type(4))) float f32x4;
typedef unsigned short u16;

#define NNODES 32768
#define NEDGES 196608

#define MFMA16(a, b, c) __builtin_amdgcn_mfma_f32_16x16x32_bf16((a), (b), (c), 0, 0, 0)

__device__ __forceinline__ u16 f2bf(float f) {
    unsigned u = __float_as_uint(f);
    unsigned r = (u + 0x7FFFu + ((u >> 16) & 1u)) >> 16;  // RNE
    return (u16)r;
}
__device__ __forceinline__ float bf2f(u16 b) {
    return __uint_as_float(((unsigned)b) << 16);
}
__device__ __forceinline__ unsigned pack2(float a, float b) {
    return (unsigned)f2bf(a) | ((unsigned)f2bf(b) << 16);
}

// ---------------------------------------------------------------------------
// Input transpose (x only): W (K, Nout) fp32 -> WT (NP, Kpad) bf16
// ---------------------------------------------------------------------------
__global__ void wtrans_kernel(const float* __restrict__ W, u16* __restrict__ WT,
                              int K, int Nout, int Kpad, int NP) {
    __shared__ u16 tile[32][33];
    const int k0 = blockIdx.x * 32, n0 = blockIdx.y * 32;
    const int tx = threadIdx.x & 31, ty = threadIdx.x >> 5;  // 32 x 8
    #pragma unroll
    for (int i = 0; i < 4; i++) {
        int k = k0 + ty + 8 * i, n = n0 + tx;
        float v = (k < K && n < Nout) ? W[(size_t)k * Nout + n] : 0.f;
        tile[ty + 8 * i][tx] = f2bf(v);
    }
    __syncthreads();
    #pragma unroll
    for (int i = 0; i < 4; i++) {
        int n = n0 + ty + 8 * i, k = k0 + tx;
        if (n < NP && k < Kpad) WT[(size_t)n * Kpad + k] = tile[tx][ty + 8 * i];
    }
}

// ---------------------------------------------------------------------------
// Fragment-major weight pack: W (batch, K, N) fp32 -> frags bf16.
// Frag (ks, cb): lane l, elem j  <-  W[k = ks*32 + (l>>4)*8 + j][n = cb*16 + (l&15)]
// ---------------------------------------------------------------------------
__global__ void fragpack_kernel(const float* __restrict__ W, u16* __restrict__ F,
                                int K, int N, int CB, int NFRAG) {
    int b = blockIdx.z;
    int fr = blockIdx.x * 4 + (threadIdx.x >> 6);
    if (fr >= NFRAG) return;
    int l = threadIdx.x & 63;
    int ks = fr / CB, cb = fr % CB;
    int k0 = ks * 32 + ((l >> 4) * 8);
    int n = cb * 16 + (l & 15);
    u16 v[8];
    #pragma unroll
    for (int j = 0; j < 8; j++) {
        int k = k0 + j;
        float x = (k < K && n < N) ? W[((size_t)b * K + k) * N + n] : 0.f;
        v[j] = f2bf(x);
    }
    *(uint4*)(F + (((size_t)b * NFRAG + fr) * 64 + l) * 8) = *(const uint4*)v;
}

// ---------------------------------------------------------------------------
// edge_index normalization (int64 payload -> int32 [src | dst])
// ---------------------------------------------------------------------------
__global__ void idx_norm_kernel(const int* __restrict__ raw, int* __restrict__ sd) {
    __shared__ int nz;
    if (threadIdx.x == 0) nz = 0;
    __syncthreads();
    for (int i = threadIdx.x; i < 512; i += 256)
        if (raw[2 * i + 1] != 0) atomicAdd(&nz, 1);
    __syncthreads();
    const bool is64 = (nz == 0);
    int idx = blockIdx.x * 256 + threadIdx.x;
    if (idx < 2 * NEDGES) sd[idx] = is64 ? raw[2 * idx] : raw[idx];
}

// ---------------------------------------------------------------------------
// CSR build (by dst) + edge sort.
// ---------------------------------------------------------------------------
__global__ void csr_count_kernel(const int* __restrict__ dsti, int* __restrict__ deg) {
    int e = blockIdx.x * 256 + threadIdx.x;
    atomicAdd(&deg[dsti[e]], 1);
}

__global__ void csr_scan_kernel(const int* __restrict__ deg, int* __restrict__ off,
                                int* __restrict__ cur) {
    __shared__ int part[1024];
    const int t = threadIdx.x;
    int local[32];
    int s = 0;
    #pragma unroll
    for (int i = 0; i < 32; i++) { local[i] = deg[t * 32 + i]; s += local[i]; }
    part[t] = s;
    __syncthreads();
    for (int d = 1; d < 1024; d <<= 1) {
        int v = (t >= d) ? part[t - d] : 0;
        __syncthreads();
        part[t] += v;
        __syncthreads();
    }
    int excl = (t == 0) ? 0 : part[t - 1];
    #pragma unroll
    for (int i = 0; i < 32; i++) {
        off[t * 32 + i] = excl;
        cur[t * 32 + i] = excl;
        excl += local[i];
    }
    if (t == 1023) off[NNODES] = excl;
}

__global__ void csr_fill_kernel(const int* __restrict__ dsti, int* __restrict__ cur,
                                int* __restrict__ perm) {
    int e = blockIdx.x * 256 + threadIdx.x;
    int pos = atomicAdd(&cur[dsti[e]], 1);
    perm[pos] = e;
}

// sorted-order src/dst arrays
__global__ void esort_kernel(const int* __restrict__ sd, const int* __restrict__ perm,
                             int* __restrict__ srcS, int* __restrict__ dstS) {
    int i = blockIdx.x * 256 + threadIdx.x;
    int e = perm[i];
    srcS[i] = sd[e];
    dstS[i] = sd[NEDGES + e];
}

// aggB[n][c] = sum over sorted edge rows off[n]..off[n+1] of edge_b[i][c]
__global__ void gather_kernel(const u16* __restrict__ edge_b,
                              const int* __restrict__ off, u16* __restrict__ aggB) {
    int idx = blockIdx.x * 256 + threadIdx.x;  // N*32 threads
    int n = idx >> 5, c = (idx & 31) * 4;
    int a = off[n], b = off[n + 1];
    float s0 = 0.f, s1 = 0.f, s2 = 0.f, s3 = 0.f;
    for (int i = a; i < b; i++) {
        uint2 v = *(const uint2*)(edge_b + (size_t)i * 128 + c);
        s0 += bf2f((u16)(v.x & 0xffff)); s1 += bf2f((u16)(v.x >> 16));
        s2 += bf2f((u16)(v.y & 0xffff)); s3 += bf2f((u16)(v.y >> 16));
    }
    uint2 o;
    o.x = pack2(s0, s1);
    o.y = pack2(s2, s3);
    *(uint2*)(aggB + (size_t)n * 128 + c) = o;
}

// ---------------------------------------------------------------------------
// Fused 2-layer MLP.  Block = 256 threads (4 waves) = 64 rows.
// GEMM1: per-step 64x32 LDS A-tile (double-buffered, 1 barrier/step),
//        A global->reg ring-of-3 (dist-3), B frag ping-pong dist-2.
// GEMM2: h via LDS (half-split), W2 ping-pong dist-2; cross-wave LN.
// Residual bf16 in-place; single bf16 store.
// IN: 0=edge(src|dst|edge)  1=node(node|aggB)  2=direct bf16 stride A1S
//     3=raw edge feats via perm (p.src = perm)
// ---------------------------------------------------------------------------
struct MlpP {
    const u16* A1;
    const u16* A1b;
    const float* Araw;
    const int* src;
    const int* dsti;
    const u16* W1F;   // frag-major [K1/32][NH/16][64][8]
    const u16* W2F;   // frag-major [NH/32][NFRAG2][64][8]
    const float* b1;
    const float* b2;
    const float* g;
    const float* bt;
    const u16* residB;
    u16* outB;
    float* outDec;
};

template <int K1, int NH, int NOUT, int IN, int OUT, int A1S>
__global__ __launch_bounds__(256, 2) void mlp_kernel(MlpP p) {
    static_assert(K1 % 32 == 0 && NH % 128 == 0, "dims");
    constexpr int KSTEPS = K1 / 32;
    constexpr int NT1 = NH / 64;                 // GEMM1 col-frags per wave
    constexpr int CB1 = NH / 16;
    constexpr int NFRAG2 = (NOUT + 15) / 16;
    constexpr int NT2 = (NFRAG2 + 3) / 4;        // GEMM2 frags per wave
    constexpr int S2 = NH / 64;                  // GEMM2 32-k steps per half
    constexpr int SH2 = NH / 2 + 8;              // padded h stride (u16)
    constexpr int SH_BYTES = 64 * SH2 * 2;
    constexpr int SMEM_I = (SH_BYTES > 8192 ? SH_BYTES : 8192);
    constexpr int SMEM = SMEM_I + 2560;          // + LN scratch

    __shared__ __align__(16) char smem[SMEM];
    u16* sA = (u16*)smem;                        // two 4KB swizzled buffers
    u16* sH = (u16*)smem;                        // [64][SH2] phase 2
    float* sS1 = (float*)(smem + SMEM_I);        // [4][64]
    float* sS2 = sS1 + 256;                      // [4][64]
    float* sMu = sS1 + 512;                      // [64]
    float* sRs = sS1 + 576;                      // [64]

    const int tid = threadIdx.x;
    const int wave = tid >> 6, lane = tid & 63;
    const int lhi = lane >> 4, llo = lane & 15;
    const int r0 = blockIdx.x * 64;
    const int key = (llo >> 1) & 3;

    // A staging: 64 rows x 4 chunks; source chunk XOR-permuted per row pair
    const int sr = tid >> 2;
    const int sg = (tid & 3) ^ ((sr >> 1) & 3);
    int gsrc = 0, gdst = 0;
    if constexpr (IN == 0) { gsrc = p.src[r0 + sr]; gdst = p.dsti[r0 + sr]; }
    if constexpr (IN == 3) { gsrc = p.src[r0 + sr]; }  // perm

    // Segment select on ks*32 (uniform per step -> folds away after unroll).
    auto loadA = [&](int ks, uint4& d) {
        const int kb = ks * 32;
        if constexpr (IN == 0) {
            if (kb < 256)      d = *(const uint4*)(p.A1 + (size_t)gsrc * 256 + kb + sg * 8);
            else if (kb < 512) d = *(const uint4*)(p.A1 + (size_t)gdst * 256 + (kb - 256) + sg * 8);
            else               d = *(const uint4*)(p.A1b + (size_t)(r0 + sr) * 128 + (kb - 512) + sg * 8);
        } else if constexpr (IN == 1) {
            if (kb < 256) d = *(const uint4*)(p.A1 + (size_t)(r0 + sr) * 256 + kb + sg * 8);
            else          d = *(const uint4*)(p.A1b + (size_t)(r0 + sr) * 128 + (kb - 256) + sg * 8);
        } else if constexpr (IN == 2) {
            d = *(const uint4*)(p.A1 + (size_t)(r0 + sr) * A1S + kb + sg * 8);
        } else {  // IN == 3 : raw edge feats via perm (3 -> 32 padded), single step
            uint4 v = {0u, 0u, 0u, 0u};
            if (sg == 0) {
                const float* q = p.Araw + (size_t)gsrc * 3;
                v.x = pack2(q[0], q[1]);
                v.y = pack2(q[2], 0.f);
            }
            d = v;
        }
    };
    auto loadB1 = [&](int ks, bf16x8 (&d)[NT1]) {
        #pragma unroll
        for (int j = 0; j < NT1; j++) {
            int cb = j * 4 + wave;
            d[j] = *(const bf16x8*)(p.W1F + ((size_t)(ks * CB1 + cb) * 64 + lane) * 8);
        }
    };

    const f32x4 fz = {0.f, 0.f, 0.f, 0.f};
    f32x4 acc[4][NT1];
    #pragma unroll
    for (int m = 0; m < 4; m++)
        #pragma unroll
        for (int j = 0; j < NT1; j++) acc[m][j] = fz;

    uint4 pa0, pa1, pa2;
    bf16x8 pb0[NT1], pb1[NT1];
    loadA(0, pa0);
    if constexpr (KSTEPS > 1) loadA(1, pa1);
    if constexpr (KSTEPS > 2) loadA(2, pa2);
    loadB1(0, pb0);
    if constexpr (KSTEPS > 1) loadB1(1, pb1);

    // ---------------- GEMM1: one barrier per step, deep prefetch ----------
    #pragma unroll
    for (int ks = 0; ks < KSTEPS; ks++) {
        uint4* sAw = (uint4*)(sA + (ks & 1) * 2048);
        sAw[tid] = (ks % 3 == 0) ? pa0 : (ks % 3 == 1) ? pa1 : pa2;
        if (ks + 3 < KSTEPS) {
            if (ks % 3 == 0) loadA(ks + 3, pa0);
            else if (ks % 3 == 1) loadA(ks + 3, pa1);
            else loadA(ks + 3, pa2);
        }
        __syncthreads();
        const u16* sAr = sA + (ks & 1) * 2048;
        bf16x8 a[4];
        #pragma unroll
        for (int m = 0; m < 4; m++)
            a[m] = *(const bf16x8*)(sAr + (m * 16 + llo) * 32 + (lhi ^ key) * 8);
        bf16x8 (&pbc)[NT1] = (ks & 1) ? pb1 : pb0;
        #pragma unroll
        for (int j = 0; j < NT1; j++)
            #pragma unroll
            for (int m = 0; m < 4; m++) acc[m][j] = MFMA16(a[m], pbc[j], acc[m][j]);
        if (ks + 2 < KSTEPS) loadB1(ks + 2, pbc);
    }
    __syncthreads();  // sH aliases sA

    // ---------------- phase 2: h halves -> LDS, GEMM2 ping-pong W2 --------
    f32x4 acc2[4][NT2];
    #pragma unroll
    for (int m = 0; m < 4; m++)
        #pragma unroll
        for (int j = 0; j < NT2; j++) acc2[m][j] = fz;

    auto loadW2 = [&](int g, bf16x8 (&d)[NT2]) {
        #pragma unroll
        for (int j = 0; j < NT2; j++) {
            int f = j * 4 + wave;
            if (NFRAG2 % 4 == 0 || f < NFRAG2)
                d[j] = *(const bf16x8*)(p.W2F + ((size_t)(g * NFRAG2 + f) * 64 + lane) * 8);
        }
    };
    bf16x8 pw0[NT2], pw1[NT2];
    loadW2(0, pw0);
    loadW2(1, pw1);

    #pragma unroll
    for (int half = 0; half < 2; half++) {
        // h-write: this wave's col-blocks of this half (SiLU via fast rcp)
        #pragma unroll
        for (int j = half * (NT1 / 2); j < (half + 1) * (NT1 / 2); j++) {
            int c = (j * 4 + wave) * 16 + llo;
            int coll = c - half * (NH / 2);
            float bias = p.b1[c];
            #pragma unroll
            for (int m = 0; m < 4; m++)
                #pragma unroll
                for (int r = 0; r < 4; r++) {
                    int row = m * 16 + lhi * 4 + r;
                    float v = acc[m][j][r] + bias;
                    float sgm = __builtin_amdgcn_rcpf(1.f + __expf(-v));
                    sH[row * SH2 + coll] = f2bf(v * sgm);
                }
        }
        __syncthreads();
        #pragma unroll
        for (int s = 0; s < S2; s++) {
            const int g = half * S2 + s;
            bf16x8 (&pwc)[NT2] = (g & 1) ? pw1 : pw0;
            bf16x8 a2[4];
            #pragma unroll
            for (int m = 0; m < 4; m++)
                a2[m] = *(const bf16x8*)(sH + (m * 16 + llo) * SH2 + s * 32 + lhi * 8);
            #pragma unroll
            for (int j = 0; j < NT2; j++)
                if (NFRAG2 % 4 == 0 || j * 4 + wave < NFRAG2)
                    #pragma unroll
                    for (int m = 0; m < 4; m++)
                        acc2[m][j] = MFMA16(a2[m], pwc[j], acc2[m][j]);
            if (g + 2 < 2 * S2) loadW2(g + 2, pwc);
        }
        __syncthreads();
    }

    // ---------------- epilogue ----------------
    if constexpr (OUT == 0) {  // +bias +resid(bf16), LayerNorm, bf16 out
        float ps1[4][4], ps2[4][4];
        #pragma unroll
        for (int m = 0; m < 4; m++)
            #pragma unroll
            for (int r = 0; r < 4; r++) { ps1[m][r] = 0.f; ps2[m][r] = 0.f; }
        #pragma unroll
        for (int j = 0; j < NT2; j++) {
            int col = (j * 4 + wave) * 16 + llo;
            float bias = p.b2[col];
            #pragma unroll
            for (int m = 0; m < 4; m++)
                #pragma unroll
                for (int r = 0; r < 4; r++) {
                    int row = m * 16 + lhi * 4 + r;
                    float v = acc2[m][j][r] + bias +
                              bf2f(p.residB[(size_t)(r0 + row) * NOUT + col]);
                    acc2[m][j][r] = v;
                    ps1[m][r] += v;
                    ps2[m][r] += v * v;
                }
        }
        #pragma unroll
        for (int mm = 1; mm < 16; mm <<= 1)
            #pragma unroll
            for (int m = 0; m < 4; m++)
                #pragma unroll
                for (int r = 0; r < 4; r++) {
                    ps1[m][r] += __shfl_xor(ps1[m][r], mm, 64);
                    ps2[m][r] += __shfl_xor(ps2[m][r], mm, 64);
                }
        if (llo == 0) {
            #pragma unroll
            for (int m = 0; m < 4; m++)
                #pragma unroll
                for (int r = 0; r < 4; r++) {
                    int row = m * 16 + lhi * 4 + r;
                    sS1[wave * 64 + row] = ps1[m][r];
                    sS2[wave * 64 + row] = ps2[m][r];
                }
        }
        __syncthreads();
        if (tid < 64) {
            float a = sS1[tid] + sS1[64 + tid] + sS1[128 + tid] + sS1[192 + tid];
            float b = sS2[tid] + sS2[64 + tid] + sS2[128 + tid] + sS2[192 + tid];
            float mu = a * (1.f / NOUT);
            float var = b * (1.f / NOUT) - mu * mu;
            sMu[tid] = mu;
            sRs[tid] = rsqrtf(var + 1e-5f);
        }
        __syncthreads();
        #pragma unroll
        for (int j = 0; j < NT2; j++) {
            int col = (j * 4 + wave) * 16 + llo;
            float gg = p.g[col], bb = p.bt[col];
            #pragma unroll
            for (int m = 0; m < 4; m++)
                #pragma unroll
                for (int r = 0; r < 4; r++) {
                    int row = m * 16 + lhi * 4 + r;
                    float v = (acc2[m][j][r] - sMu[row]) * sRs[row] * gg + bb;
                    p.outB[(size_t)(r0 + row) * NOUT + col] = f2bf(v);
                }
        }
    } else if constexpr (OUT == 1) {  // plain +bias, bf16 out
        #pragma unroll
        for (int j = 0; j < NT2; j++) {
            int col = (j * 4 + wave) * 16 + llo;
            float bias = p.b2[col];
            #pragma unroll
            for (int m = 0; m < 4; m++)
                #pragma unroll
                for (int r = 0; r < 4; r++) {
                    int row = m * 16 + lhi * 4 + r;
                    float v = acc2[m][j][r] + bias;
                    p.outB[(size_t)(r0 + row) * NOUT + col] = f2bf(v);
                }
        }
    } else {  // decoder: transposed fp32 store, ragged frags, cols < 69
        #pragma unroll
        for (int j = 0; j < NT2; j++) {
            int f = j * 4 + wave;
            int col = f * 16 + llo;
            if (f < NFRAG2 && col < 69) {
                float bias = p.b2[col];
                #pragma unroll
                for (int m = 0; m < 4; m++)
                    #pragma unroll
                    for (int r = 0; r < 4; r++) {
                        int row = m * 16 + lhi * 4 + r;
                        p.outDec[(size_t)col * NNODES + (r0 + row)] = acc2[m][j][r] + bias;
                    }
            }
        }
    }
}

// ---------------------------------------------------------------------------
extern "C" void kernel_launch(void* const* d_in, const int* in_sizes, int n_in,
                              void* d_out, int out_size, void* d_ws, size_t ws_size,
                              hipStream_t stream) {
    (void)in_sizes; (void)n_in; (void)out_size; (void)ws_size;

    const float* x       = (const float*)d_in[0];
    const int*   eidx    = (const int*)d_in[1];
    const float* raw_e   = (const float*)d_in[2];
    const float* enc_w1  = (const float*)d_in[3];
    const float* enc_b1  = (const float*)d_in[4];
    const float* enc_w2  = (const float*)d_in[5];
    const float* enc_b2  = (const float*)d_in[6];
    const float* eenc_w1 = (const float*)d_in[7];
    const float* eenc_b1 = (const float*)d_in[8];
    const float* eenc_w2 = (const float*)d_in[9];
    const float* eenc_b2 = (const float*)d_in[10];
    const float* pe_w1   = (const float*)d_in[11];
    const float* pe_b1   = (const float*)d_in[12];
    const float* pe_w2   = (const float*)d_in[13];
    const float* pe_b2   = (const float*)d_in[14];
    const float* pe_g    = (const float*)d_in[15];
    const float* pe_bt   = (const float*)d_in[16];
    const float* pn_w1   = (const float*)d_in[17];
    const float* pn_b1   = (const float*)d_in[18];
    const float* pn_w2   = (const float*)d_in[19];
    const float* pn_b2   = (const float*)d_in[20];
    const float* pn_g    = (const float*)d_in[21];
    const float* pn_bt   = (const float*)d_in[22];
    const float* dec_w1  = (const float*)d_in[23];
    const float* dec_b1  = (const float*)d_in[24];
    const float* dec_w2  = (const float*)d_in[25];
    const float* dec_b2  = (const float*)d_in[26];

    // ---- workspace carve ----
    char* ws = (char*)d_ws;
    size_t o = 0;
    auto alloc = [&](size_t bytes) -> void* {
        void* p = ws + o;
        o += (bytes + 255) & ~(size_t)255;
        return p;
    };
    u16*   node_b = (u16*)  alloc((size_t)NNODES * 256 * 2);
    u16*   edge_b = (u16*)  alloc((size_t)NEDGES * 128 * 2);   // sorted order
    u16*   aggB   = (u16*)  alloc((size_t)NNODES * 128 * 2);
    u16*   xT     = (u16*)  alloc((size_t)NNODES * 96 * 2);
    u16*   encw1F  = (u16*)alloc((size_t)96 * 256 * 2);
    u16*   encw2F  = (u16*)alloc((size_t)256 * 256 * 2);
    u16*   eencw1F = (u16*)alloc((size_t)32 * 128 * 2);
    u16*   eencw2F = (u16*)alloc((size_t)128 * 128 * 2);
    u16*   pew1F   = (u16*)alloc((size_t)8 * 640 * 512 * 2);
    u16*   pew2F   = (u16*)alloc((size_t)8 * 512 * 128 * 2);
    u16*   pnw1F   = (u16*)alloc((size_t)8 * 384 * 512 * 2);
    u16*   pnw2F   = (u16*)alloc((size_t)8 * 512 * 256 * 2);
    u16*   decw1F  = (u16*)alloc((size_t)256 * 256 * 2);
    u16*   decw2F  = (u16*)alloc((size_t)256 * 80 * 2);
    int*   sd     = (int*)  alloc((size_t)2 * NEDGES * 4);
    int*   deg    = (int*)  alloc((size_t)NNODES * 4);
    int*   off_   = (int*)  alloc((size_t)(NNODES + 1) * 4);
    int*   cur    = (int*)  alloc((size_t)NNODES * 4);
    int*   perm   = (int*)  alloc((size_t)NEDGES * 4);
    int*   srcS   = (int*)  alloc((size_t)NEDGES * 4);
    int*   dstS   = (int*)  alloc((size_t)NEDGES * 4);

    // ---- weight prep: fragment-major pack ----
    auto FP = [&](const float* W, u16* F, int K, int N, int KB, int CB, int batch) {
        int nf = KB * CB;
        dim3 g((nf + 3) / 4, 1, batch);
        fragpack_kernel<<<g, 256, 0, stream>>>(W, F, K, N, CB, nf);
    };
    FP(enc_w1,  encw1F,  70,  256, 3,  16, 1);
    FP(enc_w2,  encw2F,  256, 256, 8,  16, 1);
    FP(eenc_w1, eencw1F, 3,   128, 1,  8,  1);
    FP(eenc_w2, eencw2F, 128, 128, 4,  8,  1);
    FP(pe_w1,   pew1F,   640, 512, 20, 32, 8);
    FP(pe_w2,   pew2F,   512, 128, 16, 8,  8);
    FP(pn_w1,   pnw1F,   384, 512, 12, 32, 8);
    FP(pn_w2,   pnw2F,   512, 256, 16, 16, 8);
    FP(dec_w1,  decw1F,  256, 256, 8,  16, 1);
    FP(dec_w2,  decw2F,  256, 69,  8,  5,  1);
    {   // x (70, N) -> xT (N, 96) bf16
        dim3 g(96 / 32, NNODES / 32, 1);
        wtrans_kernel<<<g, 256, 0, stream>>>(x, xT, 70, NNODES, 96, NNODES);
    }

    // ---- indices + CSR + edge sort ----
    idx_norm_kernel<<<1536, 256, 0, stream>>>(eidx, sd);
    hipMemsetAsync(deg, 0, (size_t)NNODES * 4, stream);
    csr_count_kernel<<<NEDGES / 256, 256, 0, stream>>>(sd + NEDGES, deg);
    csr_scan_kernel<<<1, 1024, 0, stream>>>(deg, off_, cur);
    csr_fill_kernel<<<NEDGES / 256, 256, 0, stream>>>(sd + NEDGES, cur, perm);
    esort_kernel<<<NEDGES / 256, 256, 0, stream>>>(sd, perm, srcS, dstS);

    // ---- encoders ----
    {
        MlpP p{};
        p.A1 = xT; p.W1F = encw1F; p.W2F = encw2F; p.b1 = enc_b1; p.b2 = enc_b2;
        p.outB = node_b;
        mlp_kernel<96, 256, 256, 2, 1, 96><<<NNODES / 64, 256, 0, stream>>>(p);
    }
    {   // edge encoder: reads raw feats via perm, writes sorted order
        MlpP p{};
        p.Araw = raw_e; p.src = perm;
        p.W1F = eencw1F; p.W2F = eencw2F; p.b1 = eenc_b1; p.b2 = eenc_b2;
        p.outB = edge_b;
        mlp_kernel<32, 128, 128, 3, 1, 0><<<NEDGES / 64, 256, 0, stream>>>(p);
    }

    // ---- processor layers ----
    for (int l = 0; l < 8; l++) {
        {
            MlpP p{};
            p.A1 = node_b; p.A1b = edge_b; p.src = srcS; p.dsti = dstS;
            p.W1F = pew1F + (size_t)l * 640 * 512;
            p.W2F = pew2F + (size_t)l * 512 * 128;
            p.b1 = pe_b1 + l * 512; p.b2 = pe_b2 + l * 128;
            p.g = pe_g + l * 128; p.bt = pe_bt + l * 128;
            p.residB = edge_b; p.outB = edge_b;   // in-place (own rows only)
            mlp_kernel<640, 512, 128, 0, 0, 0><<<NEDGES / 64, 256, 0, stream>>>(p);
        }
        gather_kernel<<<NNODES * 32 / 256, 256, 0, stream>>>(edge_b, off_, aggB);
        {
            MlpP p{};
            p.A1 = node_b; p.A1b = aggB;
            p.W1F = pnw1F + (size_t)l * 384 * 512;
            p.W2F = pnw2F + (size_t)l * 512 * 256;
            p.b1 = pn_b1 + l * 512; p.b2 = pn_b2 + l * 256;
            p.g = pn_g + l * 256; p.bt = pn_bt + l * 256;
            p.residB = node_b; p.outB = node_b;   // in-place (own rows only)
            mlp_kernel<384, 512, 256, 1, 0, 0><<<NNODES / 64, 256, 0, stream>>>(p);
        }
    }

    // ---- decoder ----
    {
        MlpP p{};
        p.A1 = node_b; p.W1F = decw1F; p.W2F = decw2F; p.b1 = dec_b1; p.b2 = dec_b2;
        p.outDec = (float*)d_out;
        mlp_kernel<256, 256, 80, 2, 2, 256><<<NNODES / 64, 256, 0, stream>>>(p);
    }
}